// Round 10
// baseline (2530.528 us; speedup 1.0000x reference)
//
#include <hip/hip_runtime.h>
#include <cstddef>
#include <cstdint>

#define PI_F 3.14159265358979323846f

typedef __attribute__((ext_vector_type(8))) short short8;   // 8 bf16 = 4 VGPRs
typedef __attribute__((ext_vector_type(4))) float floatx4;  // MFMA acc

__device__ __forceinline__ short f2bf(float f) {
    union { float f; unsigned u; } v; v.f = f;
    unsigned r = v.u + 0x7FFFu + ((v.u >> 16) & 1u);   // RNE
    return (short)(r >> 16);
}

// ---------------------------------------------------------------------------
// Weight transpose+convert: Abf[m][k'] = bf16(A[m][c*K2 + tap]), k' = tap*Cp+c
// ---------------------------------------------------------------------------
__global__ __launch_bounds__(256) void wtrans_kernel(
    const float* __restrict__ A, short* __restrict__ Abf,
    int M, int Mpad, int K2, int C, int Cp, int Kp, int Korig)
{
    int idx = blockIdx.x * 256 + threadIdx.x;
    if (idx >= Mpad * Kp) return;
    int m = idx / Kp;
    int k = idx - m * Kp;
    int tap = (unsigned)k / (unsigned)Cp;
    int c   = k - tap * Cp;
    float v = 0.f;
    if (m < M && tap < K2 && c < C) v = A[(size_t)m * Korig + c * K2 + tap];
    Abf[idx] = f2bf(v);
}

__global__ __launch_bounds__(256) void zero_kernel(float* __restrict__ p, int n)
{
    int i = blockIdx.x * 256 + threadIdx.x;
    if (i < n) p[i] = 0.f;
}

// ---------------------------------------------------------------------------
// Fused spherical-conv GEMM, bf16 MFMA, channel-innermost K.
// ROUND-10 NOTE: this is the round-6 kernel body (inline gather, no register
// pipeline — rounds 7-9 proved the compiler demotes any source-level
// prefetch formulation to scratch: VGPR=44, +8MB scratch writes, 2.2x slower)
// plus two proven wins from r7:
//  * XCD swizzle: logical = (pid%8)*(total/8)+(pid/8), m-inner/n-major ->
//    contiguous n-range per XCD -> gather re-reads hit L2 (FETCH 488->6.6MB).
//  * Fused BN stats epilogue: per-channel sum/sumsq via 16-lane shfl_xor +
//    atomicAdd -> separate stats pass (84MB re-read) deleted.
// Block tile 64x64, BK=32, 4 waves (2x2), each wave 32x32 via 2x2
// v_mfma_f32_16x16x32_bf16. Per K-tile each thread owns ONE tap and 8
// consecutive channels: coords/weights/corner indices computed once, inner
// loop is 4 loads + 4 FMA + f2bf per channel. A frags load direct from
// global (pre-transposed Abf, L1/L2-hot).
// ---------------------------------------------------------------------------
#define BMT 64
#define BNT 64
#define BKT 32
#define LDK 40

__global__ __launch_bounds__(256) void sconv_mfma_kernel(
    const short* __restrict__ Abf, const float* __restrict__ bias,
    const float* __restrict__ src1, const float* __restrict__ src2,
    float* __restrict__ accum,
    int C1, int Ctot, int Cp, int H, int W, int up1,
    int K2, int ksz, int stride, int lWo, int lHo, float delta,
    float* __restrict__ Y, int M, int Kp, int N, int lgM)
{
    __shared__ short Bs[BNT][LDK];
    __shared__ float4 tab[64];          // max nHo*K2 = 49 over all layers

    const int tid = threadIdx.x;
    // ---- XCD swizzle (total % 8 == 0 for all layers) ----
    const int total = gridDim.x;
    const int pid = blockIdx.x;
    const int logical = (pid & 7) * (total >> 3) + (pid >> 3);
    const int m0 = (logical & ((1 << lgM) - 1)) * BMT;
    const int n0 = (logical >> lgM) * BNT;

    const int Wo  = 1 << lWo;
    const int Ho  = 1 << lHo;
    const int HW  = 1 << (lWo + lHo);

    // ---- per-block grid table: (hoLocal, tap) -> {fr, dcol, r0i, r1i} ----
    const int nHo  = (lWo >= 6) ? 1 : (BNT >> lWo);
    const int nEnt = nHo * K2;
    const int hoBase = (n0 >> lWo) & (Ho - 1);
    if (tid < nEnt) {
        int hoL = tid / K2;
        int i   = tid - hoL * K2;
        int ho_g = hoBase + hoL;
        int jy = i / ksz, jx = i - jy * ksz;
        float halfk = (ksz - 1) * 0.5f;
        float yy = tanf(delta / (float)ksz * ((float)jy - halfk));
        float xx = tanf(delta / (float)ksz * ((float)jx - halfk));
        float rho = sqrtf(xx * xx + yy * yy);
        float rho_s = (rho == 0.f) ? 1.f : rho;
        float nu = atanf(rho);
        float lat0 = PI_F * 0.5f - ((float)(ho_g * stride) + 0.5f) * (PI_F / (float)H);
        float sl = sinf(lat0), cl = cosf(lat0);
        float sn = sinf(nu),  cn = cosf(nu);
        float arg = cn * sl + (yy / rho_s) * sn * cl;
        arg = fminf(1.f, fmaxf(-1.f, arg));
        float lat = asinf(arg);
        float dlon = atan2f(xx * sn, rho * cl * cn - yy * sl * sn);
        float row = (PI_F * 0.5f - lat) / PI_F * (float)H - 0.5f;
        float dcol = dlon / (2.f * PI_F) * (float)W;
        float r0f = floorf(row);
        float fr = row - r0f;
        int r0 = (int)r0f;
        int r0i = min(max(r0, 0), H - 1);
        int r1i = min(max(r0 + 1, 0), H - 1);
        tab[tid] = make_float4(fr, dcol, __int_as_float(r0i), __int_as_float(r1i));
    }

    // ---- B staging geometry (lane nn = coalesced wo) ----
    const int nn    = tid & 63;
    const int kslot = tid >> 6;         // wave-uniform
    const int n_s  = n0 + nn;
    const int wo_s = n_s & (Wo - 1);
    const int hoL_s = nn >> lWo;
    const int b_s  = n_s >> (lWo + lHo);   // block-uniform (HW multiple of 64)
    const int tabBase = hoL_s * K2;
    const float wo_px = (float)(wo_s * stride);
    const int Hs = H >> up1, Ws = W >> up1;
    const int plane1 = Hs * Ws;
    const int plane2 = H * W;
    const unsigned boff1 = (unsigned)(b_s * C1 * plane1);
    const unsigned boff2 = (unsigned)(b_s * (Ctot - C1) * plane2);

    // ---- (tap, cb) iteration state: chunk = one tap, 8 channels ----
    const bool smallC = (Cp < 32);      // layer 1 only (Cp=8)
    int tap = smallC ? kslot : 0;
    int cb  = smallC ? 0 : kslot * 8;
    const int dtap = smallC ? (32 / Cp) : 0;

    // ---- wave/lane decomposition for MFMA ----
    const int wave = tid >> 6;
    const int wm   = (wave & 1) * 32;
    const int wn   = (wave >> 1) * 32;
    const int lane = tid & 63;
    const int l16  = lane & 15;
    const int quad = lane >> 4;

    const short* pA0 = Abf + (size_t)(m0 + wm + l16) * Kp + quad * 8;
    const short* pA1 = pA0 + (size_t)16 * Kp;

    floatx4 acc[2][2];
#pragma unroll
    for (int i = 0; i < 2; i++)
#pragma unroll
        for (int j = 0; j < 2; j++)
            acc[i][j] = (floatx4){0.f, 0.f, 0.f, 0.f};

    __syncthreads();   // table ready

    for (int k0 = 0; k0 < Kp; k0 += BKT) {
        // ---- B tile: one tap, 8 channels (inline gather, r6 structure) ----
        {
            const int tapc = min(tap, K2 - 1);       // clamp for L1 pad region
            const float4 e = tab[tabBase + tapc];
            const float fr = e.x;
            const float col = wo_px + e.y;
            const int r0i = __float_as_int(e.z);
            const int r1i = __float_as_int(e.w);
            const float cf = floorf(col);
            const float fc = col - cf;
            const int c0 = ((int)cf) & (W - 1);
            const int c1 = (c0 + 1) & (W - 1);
            const float w00 = (1.f - fr) * (1.f - fc);
            const float w01 = (1.f - fr) * fc;
            const float w10 = fr * (1.f - fc);
            const float w11 = fr * fc;

            const float* src; unsigned i00, i01, i10, i11, plane;
            if (cb < C1) {               // wave-uniform branch
                const int ra = (r0i >> up1) * Ws, rb = (r1i >> up1) * Ws;
                const int ca = c0 >> up1, cx = c1 >> up1;
                const unsigned base = boff1 + (unsigned)cb * plane1;
                i00 = base + ra + ca; i01 = base + ra + cx;
                i10 = base + rb + ca; i11 = base + rb + cx;
                plane = plane1; src = src1;
            } else {
                const int ra = r0i * W, rb = r1i * W;
                const unsigned base = boff2 + (unsigned)(cb - C1) * plane2;
                i00 = base + ra + c0; i01 = base + ra + c1;
                i10 = base + rb + c0; i11 = base + rb + c1;
                plane = plane2; src = src2;
            }
            short t8[8];
#pragma unroll
            for (int j = 0; j < 8; j++) {
                float v = 0.f;
                if (cb + j < Ctot) {     // guard BEFORE loads (L1: src2 null)
                    v = w00 * src[i00] + w01 * src[i01]
                      + w10 * src[i10] + w11 * src[i11];
                }
                t8[j] = f2bf(v);
                i00 += plane; i01 += plane; i10 += plane; i11 += plane;
            }
            *(short8*)&Bs[nn][kslot * 8] = *(short8*)&t8[0];
        }
        __syncthreads();

        const short8 af0 = *(const short8*)(pA0 + k0);
        const short8 af1 = *(const short8*)(pA1 + k0);
        const short8 b0 = *(const short8*)&Bs[wn + l16][quad * 8];
        const short8 b1 = *(const short8*)&Bs[wn + 16 + l16][quad * 8];
        acc[0][0] = __builtin_amdgcn_mfma_f32_16x16x32_bf16(af0, b0, acc[0][0], 0, 0, 0);
        acc[0][1] = __builtin_amdgcn_mfma_f32_16x16x32_bf16(af0, b1, acc[0][1], 0, 0, 0);
        acc[1][0] = __builtin_amdgcn_mfma_f32_16x16x32_bf16(af1, b0, acc[1][0], 0, 0, 0);
        acc[1][1] = __builtin_amdgcn_mfma_f32_16x16x32_bf16(af1, b1, acc[1][1], 0, 0, 0);
        __syncthreads();

        // advance (tap, cb)
        if (smallC) { tap += dtap; }
        else { cb += 32; if (cb >= Cp) { cb -= Cp; tap++; } }
    }

    // ---- epilogue: store + fused BN partial stats ----
    // C/D layout col=lane&15, row=quad*4+reg. Per (i,rr): sum over j + 16
    // lanes (shfl_xor) -> one atomicAdd pair per 16-lane group.
#pragma unroll
    for (int i = 0; i < 2; i++) {
#pragma unroll
        for (int rr = 0; rr < 4; rr++) {
            const int m = m0 + wm + i * 16 + quad * 4 + rr;
            const bool mv = (m < M);
            const float bv = mv ? bias[m] : 0.f;
            float s = 0.f, q = 0.f;
#pragma unroll
            for (int j = 0; j < 2; j++) {
                const int n = n0 + wn + j * 16 + l16;
                const float v = acc[i][j][rr] + bv;
                s += v; q += v * v;
                if (mv) {
                    const int wo = n & (Wo - 1);
                    const int r  = n >> lWo;
                    const int ho = r & (Ho - 1);
                    const int b_ = r >> lHo;
                    Y[((size_t)b_ * M + m) * HW + (ho << lWo) + wo] = v;
                }
            }
#pragma unroll
            for (int mask = 1; mask < 16; mask <<= 1) {
                s += __shfl_xor(s, mask);
                q += __shfl_xor(q, mask);
            }
            if (mv && l16 == 0) {
                atomicAdd(&accum[m * 2], s);
                atomicAdd(&accum[m * 2 + 1], q);
            }
        }
    }
}

// ---------------------------------------------------------------------------
// BN finalize + normalize + ReLU (stats read from fused accumulators).
// ---------------------------------------------------------------------------
__global__ __launch_bounds__(256) void bn_apply_kernel(
    float* __restrict__ Y, const float* __restrict__ accum,
    const float* __restrict__ g, const float* __restrict__ bb,
    int Co, int HW, int Nt, int total)
{
    int idx = blockIdx.x * 256 + threadIdx.x;
    if (idx >= total) return;
    int c = (idx / HW) % Co;           // uniform within block (256 | HW)
    float mean = accum[c * 2] / (float)Nt;
    float var = accum[c * 2 + 1] / (float)Nt - mean * mean;
    var = fmaxf(var, 0.f);
    float sc = g[c] / sqrtf(var + 1e-5f);
    float sf = bb[c] - mean * sc;
    float v = Y[idx] * sc + sf;
    Y[idx] = v > 0.f ? v : 0.f;
}

// ---------------------------------------------------------------------------
// Host orchestration. Workspace ~35 MB: accum 16KB + activations 29.4MB +
// Abf 5.1MB. Scratch Q reuse by lifetime: x1=Q (L1-2), x3=Q (L3-4),
// x4=Q (L5-6), x41=Q+512K (L6-7), x5=Q+1M (L7-8).
// ---------------------------------------------------------------------------
extern "C" void kernel_launch(void* const* d_in, const int* in_sizes, int n_in,
                              void* d_out, int out_size, void* d_ws, size_t ws_size,
                              hipStream_t stream)
{
    const int B = 4;
    char* ws = (char*)d_ws;
    size_t off = 0;
    auto allocb = [&](size_t bytes) -> void* {
        void* p = ws + off;
        off = (off + bytes + 255) & ~(size_t)255;
        return p;
    };

    float* accumAll = (float*)allocb(8 * 512 * sizeof(float));  // 8 layers x 256ch x {s,q}
    float* x2  = (float*)allocb((size_t)B * 64  * 64 * 128 * 4);
    float* x31 = (float*)allocb((size_t)B * 128 * 32 * 64 * 4);
    float* Q   = (float*)allocb((size_t)B * 32  * 128 * 256 * 4);
    float* x1  = Q;
    float* x3  = Q;
    float* x4  = Q;
    float* x41 = Q + (size_t)B * 256 * 16 * 32;
    float* x5  = Q + 2 * (size_t)B * 256 * 16 * 32;

    //                      1     2     3    31     4    41     5     6
    static const int kH[8]  = {256, 128,  64,  32,  32,  16,  32,  64};
    static const int kW[8]  = {512, 256, 128,  64,  64,  32,  64, 128};
    static const int kK[8]  = {  7,   5,   5,   3,   3,   3,   3,   3};
    static const int kSt[8] = {  2,   2,   2,   1,   2,   1,   1,   1};
    static const int kC[8]  = {  6,  32,  64, 128, 128, 256, 384, 320};
    static const int kM[8]  = { 32,  64, 128, 128, 256, 256, 256, 128};

    int Cp_[8], Kp_[8], Mpad_[8];
    short* Abf[8];
    for (int i = 0; i < 8; i++) {
        int K2 = kK[i] * kK[i];
        int Cp = (kC[i] < 8) ? 8 : kC[i];
        int Kp = (K2 * Cp + 31) & ~31;
        int Mpad = (kM[i] + 63) & ~63;
        Cp_[i] = Cp; Kp_[i] = Kp; Mpad_[i] = Mpad;
        Abf[i] = (short*)allocb((size_t)Mpad * Kp * sizeof(short));
    }
    (void)ws_size; (void)in_sizes; (void)n_in; (void)out_size;

    struct LCfg { const float *s1, *s2; int C1, up; float delta; int widx; float* Y; };
    const float* input = (const float*)d_in[0];
    LCfg L[8] = {
        { input, nullptr,   6, 0, PI_F / 32.f,  1, x1  },
        { x1,    nullptr,  32, 0, PI_F / 16.f,  5, x2  },
        { x2,    nullptr,  64, 0, PI_F / 4.f,   9, x3  },
        { x3,    nullptr, 128, 0, PI_F / 4.f,  13, x31 },
        { x31,   nullptr, 128, 0, PI_F / 2.f,  17, x4  },
        { x4,    nullptr, 256, 0, PI_F / 2.f,  21, x41 },
        { x41,   x31,     256, 1, PI_F / 4.f,  25, x5  },
        { x5,    x2,      256, 1, PI_F / 8.f,  29, (float*)d_out },
    };

    zero_kernel<<<dim3(16), dim3(256), 0, stream>>>(accumAll, 8 * 512);

    for (int i = 0; i < 8; i++) {
        const LCfg& c = L[i];
        int H = kH[i], W = kW[i], k = kK[i], st = kSt[i];
        int Ho = H / st, Wo = W / st;
        int K2 = k * k;
        int C  = kC[i], M = kM[i];
        int HW = Ho * Wo;
        int N  = B * HW;
        int lWo = __builtin_ctz(Wo), lHo = __builtin_ctz(Ho);
        const float* Wt   = (const float*)d_in[c.widx];
        const float* bias = (const float*)d_in[c.widx + 1];
        const float* gam  = (const float*)d_in[c.widx + 2];
        const float* bet  = (const float*)d_in[c.widx + 3];
        float* accum = accumAll + i * 512;

        int tn = Mpad_[i] * Kp_[i];
        wtrans_kernel<<<dim3((tn + 255) / 256), dim3(256), 0, stream>>>(
            Wt, Abf[i], M, Mpad_[i], K2, C, Cp_[i], Kp_[i], C * K2);

        int nBlkM = Mpad_[i] / BMT;
        int totalBlk = (N / BNT) * nBlkM;          // % 8 == 0 for all layers
        int lgM = __builtin_ctz(nBlkM);
        sconv_mfma_kernel<<<dim3(totalBlk), dim3(256), 0, stream>>>(
            Abf[i], bias, c.s1, c.s2, accum, c.C1, C, Cp_[i], H, W, c.up,
            K2, k, st, lWo, lHo, c.delta,
            c.Y, M, Kp_[i], N, lgM);

        int total = B * M * HW;
        bn_apply_kernel<<<dim3(total / 256), dim3(256), 0, stream>>>(
            c.Y, accum, gam, bet, M, HW, N, total);
    }
}

// Round 11
// 1386.161 us; speedup vs baseline: 1.8256x; 1.8256x over previous
//
#include <hip/hip_runtime.h>
#include <cstddef>
#include <cstdint>

#define PI_F 3.14159265358979323846f
#define SPLIT 8

typedef __attribute__((ext_vector_type(8))) short short8;   // 8 bf16 = 4 VGPRs
typedef __attribute__((ext_vector_type(4))) float floatx4;  // MFMA acc

__device__ __forceinline__ short f2bf(float f) {
    union { float f; unsigned u; } v; v.f = f;
    unsigned r = v.u + 0x7FFFu + ((v.u >> 16) & 1u);   // RNE
    return (short)(r >> 16);
}

// ---------------------------------------------------------------------------
// Weight transpose+convert: Abf[m][k'] = bf16(A[m][c*K2 + tap]), k' = tap*Cp+c
// ---------------------------------------------------------------------------
__global__ __launch_bounds__(256) void wtrans_kernel(
    const float* __restrict__ A, short* __restrict__ Abf,
    int M, int Mpad, int K2, int C, int Cp, int Kp, int Korig)
{
    int idx = blockIdx.x * 256 + threadIdx.x;
    if (idx >= Mpad * Kp) return;
    int m = idx / Kp;
    int k = idx - m * Kp;
    int tap = (unsigned)k / (unsigned)Cp;
    int c   = k - tap * Cp;
    float v = 0.f;
    if (m < M && tap < K2 && c < C) v = A[(size_t)m * Korig + c * K2 + tap];
    Abf[idx] = f2bf(v);
}

// ---------------------------------------------------------------------------
// Fused spherical-conv GEMM, bf16 MFMA, channel-innermost K.
// ROUND-11: round-6 kernel body + XCD swizzle ONLY. Rounds 7-10 isolated the
// regression to the fused atomic-BN epilogue: ~262K device-scope atomicAdds
// to a 1KB region from 1024 blocks across 8 non-coherent XCDs -> cross-XCD
// line migration serialization (+8MiB WRITE churn, ~500us on L6). Stats are
// back to a separate split-8 pass (r6-proven). The swizzle is kept: it cut
// L6 FETCH 488MB -> 6.6MB (gather re-reads become L2 hits).
// Block tile 64x64, BK=32, 4 waves (2x2), each wave 32x32 via 2x2
// v_mfma_f32_16x16x32_bf16. Per K-tile each thread owns ONE tap and 8
// consecutive channels. A frags load direct from global (pre-transposed Abf).
// ---------------------------------------------------------------------------
#define BMT 64
#define BNT 64
#define BKT 32
#define LDK 40

__global__ __launch_bounds__(256) void sconv_mfma_kernel(
    const short* __restrict__ Abf, const float* __restrict__ bias,
    const float* __restrict__ src1, const float* __restrict__ src2,
    int C1, int Ctot, int Cp, int H, int W, int up1,
    int K2, int ksz, int stride, int lWo, int lHo, float delta,
    float* __restrict__ Y, int M, int Kp, int N, int lgM)
{
    __shared__ short Bs[BNT][LDK];
    __shared__ float4 tab[64];          // max nHo*K2 = 49 over all layers

    const int tid = threadIdx.x;
    // ---- XCD swizzle (total % 8 == 0 for all layers) ----
    const int total = gridDim.x;
    const int pid = blockIdx.x;
    const int logical = (pid & 7) * (total >> 3) + (pid >> 3);
    const int m0 = (logical & ((1 << lgM) - 1)) * BMT;
    const int n0 = (logical >> lgM) * BNT;

    const int Wo  = 1 << lWo;
    const int Ho  = 1 << lHo;
    const int HW  = 1 << (lWo + lHo);

    // ---- per-block grid table: (hoLocal, tap) -> {fr, dcol, r0i, r1i} ----
    const int nHo  = (lWo >= 6) ? 1 : (BNT >> lWo);
    const int nEnt = nHo * K2;
    const int hoBase = (n0 >> lWo) & (Ho - 1);
    if (tid < nEnt) {
        int hoL = tid / K2;
        int i   = tid - hoL * K2;
        int ho_g = hoBase + hoL;
        int jy = i / ksz, jx = i - jy * ksz;
        float halfk = (ksz - 1) * 0.5f;
        float yy = tanf(delta / (float)ksz * ((float)jy - halfk));
        float xx = tanf(delta / (float)ksz * ((float)jx - halfk));
        float rho = sqrtf(xx * xx + yy * yy);
        float rho_s = (rho == 0.f) ? 1.f : rho;
        float nu = atanf(rho);
        float lat0 = PI_F * 0.5f - ((float)(ho_g * stride) + 0.5f) * (PI_F / (float)H);
        float sl = sinf(lat0), cl = cosf(lat0);
        float sn = sinf(nu),  cn = cosf(nu);
        float arg = cn * sl + (yy / rho_s) * sn * cl;
        arg = fminf(1.f, fmaxf(-1.f, arg));
        float lat = asinf(arg);
        float dlon = atan2f(xx * sn, rho * cl * cn - yy * sl * sn);
        float row = (PI_F * 0.5f - lat) / PI_F * (float)H - 0.5f;
        float dcol = dlon / (2.f * PI_F) * (float)W;
        float r0f = floorf(row);
        float fr = row - r0f;
        int r0 = (int)r0f;
        int r0i = min(max(r0, 0), H - 1);
        int r1i = min(max(r0 + 1, 0), H - 1);
        tab[tid] = make_float4(fr, dcol, __int_as_float(r0i), __int_as_float(r1i));
    }

    // ---- B staging geometry (lane nn = coalesced wo) ----
    const int nn    = tid & 63;
    const int kslot = tid >> 6;         // wave-uniform
    const int n_s  = n0 + nn;
    const int wo_s = n_s & (Wo - 1);
    const int hoL_s = nn >> lWo;
    const int b_s  = n_s >> (lWo + lHo);   // block-uniform (HW multiple of 64)
    const int tabBase = hoL_s * K2;
    const float wo_px = (float)(wo_s * stride);
    const int Hs = H >> up1, Ws = W >> up1;
    const int plane1 = Hs * Ws;
    const int plane2 = H * W;
    const unsigned boff1 = (unsigned)(b_s * C1 * plane1);
    const unsigned boff2 = (unsigned)(b_s * (Ctot - C1) * plane2);

    // ---- (tap, cb) iteration state: chunk = one tap, 8 channels ----
    const bool smallC = (Cp < 32);      // layer 1 only (Cp=8)
    int tap = smallC ? kslot : 0;
    int cb  = smallC ? 0 : kslot * 8;
    const int dtap = smallC ? (32 / Cp) : 0;

    // ---- wave/lane decomposition for MFMA ----
    const int wave = tid >> 6;
    const int wm   = (wave & 1) * 32;
    const int wn   = (wave >> 1) * 32;
    const int lane = tid & 63;
    const int l16  = lane & 15;
    const int quad = lane >> 4;

    const short* pA0 = Abf + (size_t)(m0 + wm + l16) * Kp + quad * 8;
    const short* pA1 = pA0 + (size_t)16 * Kp;

    floatx4 acc[2][2];
#pragma unroll
    for (int i = 0; i < 2; i++)
#pragma unroll
        for (int j = 0; j < 2; j++)
            acc[i][j] = (floatx4){0.f, 0.f, 0.f, 0.f};

    __syncthreads();   // table ready

    for (int k0 = 0; k0 < Kp; k0 += BKT) {
        // ---- B tile: one tap, 8 channels (inline gather) ----
        {
            const int tapc = min(tap, K2 - 1);       // clamp for L1 pad region
            const float4 e = tab[tabBase + tapc];
            const float fr = e.x;
            const float col = wo_px + e.y;
            const int r0i = __float_as_int(e.z);
            const int r1i = __float_as_int(e.w);
            const float cf = floorf(col);
            const float fc = col - cf;
            const int c0 = ((int)cf) & (W - 1);
            const int c1 = (c0 + 1) & (W - 1);
            const float w00 = (1.f - fr) * (1.f - fc);
            const float w01 = (1.f - fr) * fc;
            const float w10 = fr * (1.f - fc);
            const float w11 = fr * fc;

            const float* src; unsigned i00, i01, i10, i11, plane;
            if (cb < C1) {               // wave-uniform branch
                const int ra = (r0i >> up1) * Ws, rb = (r1i >> up1) * Ws;
                const int ca = c0 >> up1, cx = c1 >> up1;
                const unsigned base = boff1 + (unsigned)cb * plane1;
                i00 = base + ra + ca; i01 = base + ra + cx;
                i10 = base + rb + ca; i11 = base + rb + cx;
                plane = plane1; src = src1;
            } else {
                const int ra = r0i * W, rb = r1i * W;
                const unsigned base = boff2 + (unsigned)(cb - C1) * plane2;
                i00 = base + ra + c0; i01 = base + ra + c1;
                i10 = base + rb + c0; i11 = base + rb + c1;
                plane = plane2; src = src2;
            }
            short t8[8];
#pragma unroll
            for (int j = 0; j < 8; j++) {
                float v = 0.f;
                if (cb + j < Ctot) {     // guard BEFORE loads (L1: src2 null)
                    v = w00 * src[i00] + w01 * src[i01]
                      + w10 * src[i10] + w11 * src[i11];
                }
                t8[j] = f2bf(v);
                i00 += plane; i01 += plane; i10 += plane; i11 += plane;
            }
            *(short8*)&Bs[nn][kslot * 8] = *(short8*)&t8[0];
        }
        __syncthreads();

        const short8 af0 = *(const short8*)(pA0 + k0);
        const short8 af1 = *(const short8*)(pA1 + k0);
        const short8 b0 = *(const short8*)&Bs[wn + l16][quad * 8];
        const short8 b1 = *(const short8*)&Bs[wn + 16 + l16][quad * 8];
        acc[0][0] = __builtin_amdgcn_mfma_f32_16x16x32_bf16(af0, b0, acc[0][0], 0, 0, 0);
        acc[0][1] = __builtin_amdgcn_mfma_f32_16x16x32_bf16(af0, b1, acc[0][1], 0, 0, 0);
        acc[1][0] = __builtin_amdgcn_mfma_f32_16x16x32_bf16(af1, b0, acc[1][0], 0, 0, 0);
        acc[1][1] = __builtin_amdgcn_mfma_f32_16x16x32_bf16(af1, b1, acc[1][1], 0, 0, 0);
        __syncthreads();

        // advance (tap, cb)
        if (smallC) { tap += dtap; }
        else { cb += 32; if (cb >= Cp) { cb -= Cp; tap++; } }
    }

    // ---- epilogue: plain store (C/D layout col=lane&15, row=quad*4+reg) ----
#pragma unroll
    for (int i = 0; i < 2; i++) {
#pragma unroll
        for (int j = 0; j < 2; j++) {
            const int n = n0 + wn + j * 16 + l16;
            const int wo = n & (Wo - 1);
            const int r  = n >> lWo;
            const int ho = r & (Ho - 1);
            const int b_ = r >> lHo;
#pragma unroll
            for (int rr = 0; rr < 4; rr++) {
                const int m = m0 + wm + i * 16 + quad * 4 + rr;
                if (m < M)
                    Y[((size_t)b_ * M + m) * HW + (ho << lWo) + wo] =
                        acc[i][j][rr] + bias[m];
            }
        }
    }
}

// ---------------------------------------------------------------------------
// BN stats, split 8-way per channel: partial sums (double) — r6-proven.
// ---------------------------------------------------------------------------
__global__ __launch_bounds__(256) void bn_stats_part_kernel(
    const float* __restrict__ Y, double* __restrict__ part,
    int Co, int HW, int B)
{
    int co = blockIdx.x;
    int sp = blockIdx.y;
    int tid = threadIdx.x;
    int Nt = B * HW;
    int len = (Nt + SPLIT - 1) / SPLIT;
    int start = sp * len;
    int end = min(Nt, start + len);
    double s = 0.0, s2 = 0.0;
    for (int idx = start + tid; idx < end; idx += 256) {
        int b = idx / HW; int o = idx - b * HW;
        float v = Y[((size_t)b * Co + co) * HW + o];
        s += v; s2 += (double)v * v;
    }
    __shared__ double sh_s[256], sh_s2[256];
    sh_s[tid] = s; sh_s2[tid] = s2;
    __syncthreads();
    for (int off = 128; off > 0; off >>= 1) {
        if (tid < off) { sh_s[tid] += sh_s[tid + off]; sh_s2[tid] += sh_s2[tid + off]; }
        __syncthreads();
    }
    if (tid == 0) {
        part[(co * SPLIT + sp) * 2]     = sh_s[0];
        part[(co * SPLIT + sp) * 2 + 1] = sh_s2[0];
    }
}

// Finalize (per-block, channel uniform since 256 | HW) + normalize + ReLU.
__global__ __launch_bounds__(256) void bn_apply_kernel(
    float* __restrict__ Y, const double* __restrict__ part,
    const float* __restrict__ g, const float* __restrict__ bb,
    int Co, int HW, int B, int total)
{
    int idx = blockIdx.x * 256 + threadIdx.x;
    int c = (idx / HW) % Co;           // uniform within block
    __shared__ float s_sc, s_sf;
    if (threadIdx.x == 0) {
        double s = 0.0, s2 = 0.0;
        for (int p = 0; p < SPLIT; p++) {
            s  += part[(c * SPLIT + p) * 2];
            s2 += part[(c * SPLIT + p) * 2 + 1];
        }
        int Nt = B * HW;
        double mean = s / Nt;
        double var = s2 / Nt - mean * mean;
        if (var < 0.0) var = 0.0;
        float sc = g[c] / sqrtf((float)var + 1e-5f);
        s_sc = sc;
        s_sf = bb[c] - (float)mean * sc;
    }
    __syncthreads();
    if (idx >= total) return;
    float v = Y[idx] * s_sc + s_sf;
    Y[idx] = v > 0.f ? v : 0.f;
}

// ---------------------------------------------------------------------------
// Host orchestration. Workspace ~35 MB: partials 32KB + activations 29.4MB +
// Abf 5.1MB. Scratch Q reuse by lifetime: x1=Q (L1-2), x3=Q (L3-4),
// x4=Q (L5-6), x41=Q+512K (L6-7), x5=Q+1M (L7-8).
// ---------------------------------------------------------------------------
extern "C" void kernel_launch(void* const* d_in, const int* in_sizes, int n_in,
                              void* d_out, int out_size, void* d_ws, size_t ws_size,
                              hipStream_t stream)
{
    const int B = 4;
    char* ws = (char*)d_ws;
    size_t off = 0;
    auto allocb = [&](size_t bytes) -> void* {
        void* p = ws + off;
        off = (off + bytes + 255) & ~(size_t)255;
        return p;
    };

    double* part = (double*)allocb(256 * SPLIT * 2 * sizeof(double));
    float* x2  = (float*)allocb((size_t)B * 64  * 64 * 128 * 4);
    float* x31 = (float*)allocb((size_t)B * 128 * 32 * 64 * 4);
    float* Q   = (float*)allocb((size_t)B * 32  * 128 * 256 * 4);
    float* x1  = Q;
    float* x3  = Q;
    float* x4  = Q;
    float* x41 = Q + (size_t)B * 256 * 16 * 32;
    float* x5  = Q + 2 * (size_t)B * 256 * 16 * 32;

    //                      1     2     3    31     4    41     5     6
    static const int kH[8]  = {256, 128,  64,  32,  32,  16,  32,  64};
    static const int kW[8]  = {512, 256, 128,  64,  64,  32,  64, 128};
    static const int kK[8]  = {  7,   5,   5,   3,   3,   3,   3,   3};
    static const int kSt[8] = {  2,   2,   2,   1,   2,   1,   1,   1};
    static const int kC[8]  = {  6,  32,  64, 128, 128, 256, 384, 320};
    static const int kM[8]  = { 32,  64, 128, 128, 256, 256, 256, 128};

    int Cp_[8], Kp_[8], Mpad_[8];
    short* Abf[8];
    for (int i = 0; i < 8; i++) {
        int K2 = kK[i] * kK[i];
        int Cp = (kC[i] < 8) ? 8 : kC[i];
        int Kp = (K2 * Cp + 31) & ~31;
        int Mpad = (kM[i] + 63) & ~63;
        Cp_[i] = Cp; Kp_[i] = Kp; Mpad_[i] = Mpad;
        Abf[i] = (short*)allocb((size_t)Mpad * Kp * sizeof(short));
    }
    (void)ws_size; (void)in_sizes; (void)n_in; (void)out_size;

    struct LCfg { const float *s1, *s2; int C1, up; float delta; int widx; float* Y; };
    const float* input = (const float*)d_in[0];
    LCfg L[8] = {
        { input, nullptr,   6, 0, PI_F / 32.f,  1, x1  },
        { x1,    nullptr,  32, 0, PI_F / 16.f,  5, x2  },
        { x2,    nullptr,  64, 0, PI_F / 4.f,   9, x3  },
        { x3,    nullptr, 128, 0, PI_F / 4.f,  13, x31 },
        { x31,   nullptr, 128, 0, PI_F / 2.f,  17, x4  },
        { x4,    nullptr, 256, 0, PI_F / 2.f,  21, x41 },
        { x41,   x31,     256, 1, PI_F / 4.f,  25, x5  },
        { x5,    x2,      256, 1, PI_F / 8.f,  29, (float*)d_out },
    };

    for (int i = 0; i < 8; i++) {
        const LCfg& c = L[i];
        int H = kH[i], W = kW[i], k = kK[i], st = kSt[i];
        int Ho = H / st, Wo = W / st;
        int K2 = k * k;
        int C  = kC[i], M = kM[i];
        int HW = Ho * Wo;
        int N  = B * HW;
        int lWo = __builtin_ctz(Wo), lHo = __builtin_ctz(Ho);
        const float* Wt   = (const float*)d_in[c.widx];
        const float* bias = (const float*)d_in[c.widx + 1];
        const float* gam  = (const float*)d_in[c.widx + 2];
        const float* bet  = (const float*)d_in[c.widx + 3];

        int tn = Mpad_[i] * Kp_[i];
        wtrans_kernel<<<dim3((tn + 255) / 256), dim3(256), 0, stream>>>(
            Wt, Abf[i], M, Mpad_[i], K2, C, Cp_[i], Kp_[i], C * K2);

        int nBlkM = Mpad_[i] / BMT;
        int totalBlk = (N / BNT) * nBlkM;          // % 8 == 0 for all layers
        int lgM = __builtin_ctz(nBlkM);
        sconv_mfma_kernel<<<dim3(totalBlk), dim3(256), 0, stream>>>(
            Abf[i], bias, c.s1, c.s2, c.C1, C, Cp_[i], H, W, c.up,
            K2, k, st, lWo, lHo, c.delta,
            c.Y, M, Kp_[i], N, lgM);

        bn_stats_part_kernel<<<dim3(M, SPLIT), dim3(256), 0, stream>>>(
            c.Y, part, M, HW, B);
        int total = B * M * HW;
        bn_apply_kernel<<<dim3(total / 256), dim3(256), 0, stream>>>(
            c.Y, part, gam, bet, M, HW, B, total);
    }
}

// Round 12
// 1335.979 us; speedup vs baseline: 1.8941x; 1.0376x over previous
//
#include <hip/hip_runtime.h>
#include <cstddef>
#include <cstdint>

#define PI_F 3.14159265358979323846f
#define SPLIT 8

typedef __attribute__((ext_vector_type(8))) short short8;   // 8 bf16 = 4 VGPRs
typedef __attribute__((ext_vector_type(4))) float floatx4;  // MFMA acc

__device__ __forceinline__ short f2bf(float f) {
    union { float f; unsigned u; } v; v.f = f;
    unsigned r = v.u + 0x7FFFu + ((v.u >> 16) & 1u);   // RNE
    return (short)(r >> 16);
}

// ---------------------------------------------------------------------------
// Weight transpose+convert: Abf[m][k'] = bf16(A[m][c*K2 + tap]), k' = tap*Cp+c
// ---------------------------------------------------------------------------
__global__ __launch_bounds__(256) void wtrans_kernel(
    const float* __restrict__ A, short* __restrict__ Abf,
    int M, int Mpad, int K2, int C, int Cp, int Kp, int Korig)
{
    int idx = blockIdx.x * 256 + threadIdx.x;
    if (idx >= Mpad * Kp) return;
    int m = idx / Kp;
    int k = idx - m * Kp;
    int tap = (unsigned)k / (unsigned)Cp;
    int c   = k - tap * Cp;
    float v = 0.f;
    if (m < M && tap < K2 && c < C) v = A[(size_t)m * Korig + c * K2 + tap];
    Abf[idx] = f2bf(v);
}

// ---------------------------------------------------------------------------
// Fused spherical-conv GEMM, bf16 MFMA, channel-innermost K.
// ROUND-12: r11 structure (XCD swizzle + separate BN pass — r7-r10 proved
// fused atomics poison cross-XCD) + templated m-tile width MW:
//   wave tile = MW*16 rows x 64 cols, 4 waves stacked in m -> BMT = MW*64.
// MW=2 halves the gather redundancy (B column re-gathered once per m-block)
// for layers with Mpad>=128, at +16 acc VGPRs. Used only where block count
// stays >=128 (L3/L31/L5/L6); small-N layers keep MW=1 (r3: low block count
// = latency cliff).
// ---------------------------------------------------------------------------
#define BNT 64
#define BKT 32
#define LDK 40

template<int MW>
__global__ __launch_bounds__(256) void sconv_mfma_kernel(
    const short* __restrict__ Abf, const float* __restrict__ bias,
    const float* __restrict__ src1, const float* __restrict__ src2,
    int C1, int Ctot, int Cp, int H, int W, int up1,
    int K2, int ksz, int stride, int lWo, int lHo, float delta,
    float* __restrict__ Y, int M, int Kp, int N, int lgM)
{
    __shared__ short Bs[BNT][LDK];
    __shared__ float4 tab[64];          // max nHo*K2 = 49 over all layers

    const int tid = threadIdx.x;
    // ---- XCD swizzle (total % 8 == 0 for all layers) ----
    const int total = gridDim.x;
    const int pid = blockIdx.x;
    const int logical = (pid & 7) * (total >> 3) + (pid >> 3);
    const int m0 = (logical & ((1 << lgM) - 1)) * (MW * 64);
    const int n0 = (logical >> lgM) * BNT;

    const int Wo  = 1 << lWo;
    const int Ho  = 1 << lHo;
    const int HW  = 1 << (lWo + lHo);

    // ---- per-block grid table: (hoLocal, tap) -> {fr, dcol, r0i, r1i} ----
    const int nHo  = (lWo >= 6) ? 1 : (BNT >> lWo);
    const int nEnt = nHo * K2;
    const int hoBase = (n0 >> lWo) & (Ho - 1);
    if (tid < nEnt) {
        int hoL = tid / K2;
        int i   = tid - hoL * K2;
        int ho_g = hoBase + hoL;
        int jy = i / ksz, jx = i - jy * ksz;
        float halfk = (ksz - 1) * 0.5f;
        float yy = tanf(delta / (float)ksz * ((float)jy - halfk));
        float xx = tanf(delta / (float)ksz * ((float)jx - halfk));
        float rho = sqrtf(xx * xx + yy * yy);
        float rho_s = (rho == 0.f) ? 1.f : rho;
        float nu = atanf(rho);
        float lat0 = PI_F * 0.5f - ((float)(ho_g * stride) + 0.5f) * (PI_F / (float)H);
        float sl = sinf(lat0), cl = cosf(lat0);
        float sn = sinf(nu),  cn = cosf(nu);
        float arg = cn * sl + (yy / rho_s) * sn * cl;
        arg = fminf(1.f, fmaxf(-1.f, arg));
        float lat = asinf(arg);
        float dlon = atan2f(xx * sn, rho * cl * cn - yy * sl * sn);
        float row = (PI_F * 0.5f - lat) / PI_F * (float)H - 0.5f;
        float dcol = dlon / (2.f * PI_F) * (float)W;
        float r0f = floorf(row);
        float fr = row - r0f;
        int r0 = (int)r0f;
        int r0i = min(max(r0, 0), H - 1);
        int r1i = min(max(r0 + 1, 0), H - 1);
        tab[tid] = make_float4(fr, dcol, __int_as_float(r0i), __int_as_float(r1i));
    }

    // ---- B staging geometry (lane nn = coalesced wo) ----
    const int nn    = tid & 63;
    const int kslot = tid >> 6;         // wave-uniform
    const int n_s  = n0 + nn;
    const int wo_s = n_s & (Wo - 1);
    const int hoL_s = nn >> lWo;
    const int b_s  = n_s >> (lWo + lHo);   // block-uniform (HW multiple of 64)
    const int tabBase = hoL_s * K2;
    const float wo_px = (float)(wo_s * stride);
    const int Hs = H >> up1, Ws = W >> up1;
    const int plane1 = Hs * Ws;
    const int plane2 = H * W;
    const unsigned boff1 = (unsigned)(b_s * C1 * plane1);
    const unsigned boff2 = (unsigned)(b_s * (Ctot - C1) * plane2);

    // ---- (tap, cb) iteration state: chunk = one tap, 8 channels ----
    const bool smallC = (Cp < 32);      // layer 1 only (Cp=8)
    int tap = smallC ? kslot : 0;
    int cb  = smallC ? 0 : kslot * 8;
    const int dtap = smallC ? (32 / Cp) : 0;

    // ---- wave/lane decomposition: wave tile = MW*16 rows x 64 cols ----
    const int wave = tid >> 6;
    const int wrow = wave * (MW * 16);
    const int lane = tid & 63;
    const int l16  = lane & 15;
    const int quad = lane >> 4;

    const short* pA[MW];
#pragma unroll
    for (int i = 0; i < MW; i++)
        pA[i] = Abf + (size_t)(m0 + wrow + i * 16 + l16) * Kp + quad * 8;

    floatx4 acc[MW][4];
#pragma unroll
    for (int i = 0; i < MW; i++)
#pragma unroll
        for (int j = 0; j < 4; j++)
            acc[i][j] = (floatx4){0.f, 0.f, 0.f, 0.f};

    __syncthreads();   // table ready

    for (int k0 = 0; k0 < Kp; k0 += BKT) {
        // ---- B tile: one tap, 8 channels (inline gather) ----
        {
            const int tapc = min(tap, K2 - 1);       // clamp for L1 pad region
            const float4 e = tab[tabBase + tapc];
            const float fr = e.x;
            const float col = wo_px + e.y;
            const int r0i = __float_as_int(e.z);
            const int r1i = __float_as_int(e.w);
            const float cf = floorf(col);
            const float fc = col - cf;
            const int c0 = ((int)cf) & (W - 1);
            const int c1 = (c0 + 1) & (W - 1);
            const float w00 = (1.f - fr) * (1.f - fc);
            const float w01 = (1.f - fr) * fc;
            const float w10 = fr * (1.f - fc);
            const float w11 = fr * fc;

            const float* src; unsigned i00, i01, i10, i11, plane;
            if (cb < C1) {               // wave-uniform branch
                const int ra = (r0i >> up1) * Ws, rb = (r1i >> up1) * Ws;
                const int ca = c0 >> up1, cx = c1 >> up1;
                const unsigned base = boff1 + (unsigned)cb * plane1;
                i00 = base + ra + ca; i01 = base + ra + cx;
                i10 = base + rb + ca; i11 = base + rb + cx;
                plane = plane1; src = src1;
            } else {
                const int ra = r0i * W, rb = r1i * W;
                const unsigned base = boff2 + (unsigned)(cb - C1) * plane2;
                i00 = base + ra + c0; i01 = base + ra + c1;
                i10 = base + rb + c0; i11 = base + rb + c1;
                plane = plane2; src = src2;
            }
            short t8[8];
#pragma unroll
            for (int j = 0; j < 8; j++) {
                float v = 0.f;
                if (cb + j < Ctot) {     // guard BEFORE loads (L1: src2 null)
                    v = w00 * src[i00] + w01 * src[i01]
                      + w10 * src[i10] + w11 * src[i11];
                }
                t8[j] = f2bf(v);
                i00 += plane; i01 += plane; i10 += plane; i11 += plane;
            }
            *(short8*)&Bs[nn][kslot * 8] = *(short8*)&t8[0];
        }
        __syncthreads();

        short8 af[MW];
#pragma unroll
        for (int i = 0; i < MW; i++)
            af[i] = *(const short8*)(pA[i] + k0);
        short8 bf[4];
#pragma unroll
        for (int j = 0; j < 4; j++)
            bf[j] = *(const short8*)&Bs[j * 16 + l16][quad * 8];
#pragma unroll
        for (int i = 0; i < MW; i++)
#pragma unroll
            for (int j = 0; j < 4; j++)
                acc[i][j] = __builtin_amdgcn_mfma_f32_16x16x32_bf16(
                    af[i], bf[j], acc[i][j], 0, 0, 0);
        __syncthreads();

        // advance (tap, cb)
        if (smallC) { tap += dtap; }
        else { cb += 32; if (cb >= Cp) { cb -= Cp; tap++; } }
    }

    // ---- epilogue: plain store (C/D layout col=lane&15, row=quad*4+reg) ----
#pragma unroll
    for (int i = 0; i < MW; i++) {
#pragma unroll
        for (int j = 0; j < 4; j++) {
            const int n = n0 + j * 16 + l16;
            const int wo = n & (Wo - 1);
            const int r  = n >> lWo;
            const int ho = r & (Ho - 1);
            const int b_ = r >> lHo;
#pragma unroll
            for (int rr = 0; rr < 4; rr++) {
                const int m = m0 + wrow + i * 16 + quad * 4 + rr;
                if (m < M)
                    Y[((size_t)b_ * M + m) * HW + (ho << lWo) + wo] =
                        acc[i][j][rr] + bias[m];
            }
        }
    }
}

// ---------------------------------------------------------------------------
// BN stats, split 8-way per channel: partial sums (double) — r6-proven.
// ---------------------------------------------------------------------------
__global__ __launch_bounds__(256) void bn_stats_part_kernel(
    const float* __restrict__ Y, double* __restrict__ part,
    int Co, int HW, int B)
{
    int co = blockIdx.x;
    int sp = blockIdx.y;
    int tid = threadIdx.x;
    int Nt = B * HW;
    int len = (Nt + SPLIT - 1) / SPLIT;
    int start = sp * len;
    int end = min(Nt, start + len);
    double s = 0.0, s2 = 0.0;
    for (int idx = start + tid; idx < end; idx += 256) {
        int b = idx / HW; int o = idx - b * HW;
        float v = Y[((size_t)b * Co + co) * HW + o];
        s += v; s2 += (double)v * v;
    }
    __shared__ double sh_s[256], sh_s2[256];
    sh_s[tid] = s; sh_s2[tid] = s2;
    __syncthreads();
    for (int off = 128; off > 0; off >>= 1) {
        if (tid < off) { sh_s[tid] += sh_s[tid + off]; sh_s2[tid] += sh_s2[tid + off]; }
        __syncthreads();
    }
    if (tid == 0) {
        part[(co * SPLIT + sp) * 2]     = sh_s[0];
        part[(co * SPLIT + sp) * 2 + 1] = sh_s2[0];
    }
}

// Finalize (per-block, channel uniform since 256 | HW) + normalize + ReLU.
__global__ __launch_bounds__(256) void bn_apply_kernel(
    float* __restrict__ Y, const double* __restrict__ part,
    const float* __restrict__ g, const float* __restrict__ bb,
    int Co, int HW, int B, int total)
{
    int idx = blockIdx.x * 256 + threadIdx.x;
    int c = (idx / HW) % Co;           // uniform within block
    __shared__ float s_sc, s_sf;
    if (threadIdx.x == 0) {
        double s = 0.0, s2 = 0.0;
        for (int p = 0; p < SPLIT; p++) {
            s  += part[(c * SPLIT + p) * 2];
            s2 += part[(c * SPLIT + p) * 2 + 1];
        }
        int Nt = B * HW;
        double mean = s / Nt;
        double var = s2 / Nt - mean * mean;
        if (var < 0.0) var = 0.0;
        float sc = g[c] / sqrtf((float)var + 1e-5f);
        s_sc = sc;
        s_sf = bb[c] - (float)mean * sc;
    }
    __syncthreads();
    if (idx >= total) return;
    float v = Y[idx] * s_sc + s_sf;
    Y[idx] = v > 0.f ? v : 0.f;
}

// ---------------------------------------------------------------------------
// Host orchestration. Workspace ~35 MB: partials 32KB + activations 29.4MB +
// Abf 5.1MB. Scratch Q reuse by lifetime: x1=Q (L1-2), x3=Q (L3-4),
// x4=Q (L5-6), x41=Q+512K (L6-7), x5=Q+1M (L7-8).
// ---------------------------------------------------------------------------
extern "C" void kernel_launch(void* const* d_in, const int* in_sizes, int n_in,
                              void* d_out, int out_size, void* d_ws, size_t ws_size,
                              hipStream_t stream)
{
    const int B = 4;
    char* ws = (char*)d_ws;
    size_t off = 0;
    auto allocb = [&](size_t bytes) -> void* {
        void* p = ws + off;
        off = (off + bytes + 255) & ~(size_t)255;
        return p;
    };

    double* part = (double*)allocb(256 * SPLIT * 2 * sizeof(double));
    float* x2  = (float*)allocb((size_t)B * 64  * 64 * 128 * 4);
    float* x31 = (float*)allocb((size_t)B * 128 * 32 * 64 * 4);
    float* Q   = (float*)allocb((size_t)B * 32  * 128 * 256 * 4);
    float* x1  = Q;
    float* x3  = Q;
    float* x4  = Q;
    float* x41 = Q + (size_t)B * 256 * 16 * 32;
    float* x5  = Q + 2 * (size_t)B * 256 * 16 * 32;

    //                      1     2     3    31     4    41     5     6
    static const int kH[8]  = {256, 128,  64,  32,  32,  16,  32,  64};
    static const int kW[8]  = {512, 256, 128,  64,  64,  32,  64, 128};
    static const int kK[8]  = {  7,   5,   5,   3,   3,   3,   3,   3};
    static const int kSt[8] = {  2,   2,   2,   1,   2,   1,   1,   1};
    static const int kC[8]  = {  6,  32,  64, 128, 128, 256, 384, 320};
    static const int kM[8]  = { 32,  64, 128, 128, 256, 256, 256, 128};
    // MW=2 (BMT=128) where Mpad>=128 AND resulting block count >=128:
    //                      1   2   3  31   4  41   5   6
    static const int kMW[8] = { 1,  1,  2,  2,  1,  1,  2,  2};

    int Cp_[8], Kp_[8], Mpad_[8];
    short* Abf[8];
    for (int i = 0; i < 8; i++) {
        int K2 = kK[i] * kK[i];
        int Cp = (kC[i] < 8) ? 8 : kC[i];
        int Kp = (K2 * Cp + 31) & ~31;
        int Mpad = (kM[i] + 63) & ~63;
        Cp_[i] = Cp; Kp_[i] = Kp; Mpad_[i] = Mpad;
        Abf[i] = (short*)allocb((size_t)Mpad * Kp * sizeof(short));
    }
    (void)ws_size; (void)in_sizes; (void)n_in; (void)out_size;

    struct LCfg { const float *s1, *s2; int C1, up; float delta; int widx; float* Y; };
    const float* input = (const float*)d_in[0];
    LCfg L[8] = {
        { input, nullptr,   6, 0, PI_F / 32.f,  1, x1  },
        { x1,    nullptr,  32, 0, PI_F / 16.f,  5, x2  },
        { x2,    nullptr,  64, 0, PI_F / 4.f,   9, x3  },
        { x3,    nullptr, 128, 0, PI_F / 4.f,  13, x31 },
        { x31,   nullptr, 128, 0, PI_F / 2.f,  17, x4  },
        { x4,    nullptr, 256, 0, PI_F / 2.f,  21, x41 },
        { x41,   x31,     256, 1, PI_F / 4.f,  25, x5  },
        { x5,    x2,      256, 1, PI_F / 8.f,  29, (float*)d_out },
    };

    for (int i = 0; i < 8; i++) {
        const LCfg& c = L[i];
        int H = kH[i], W = kW[i], k = kK[i], st = kSt[i];
        int Ho = H / st, Wo = W / st;
        int K2 = k * k;
        int C  = kC[i], M = kM[i];
        int HW = Ho * Wo;
        int N  = B * HW;
        int lWo = __builtin_ctz(Wo), lHo = __builtin_ctz(Ho);
        const float* Wt   = (const float*)d_in[c.widx];
        const float* bias = (const float*)d_in[c.widx + 1];
        const float* gam  = (const float*)d_in[c.widx + 2];
        const float* bet  = (const float*)d_in[c.widx + 3];

        int tn = Mpad_[i] * Kp_[i];
        wtrans_kernel<<<dim3((tn + 255) / 256), dim3(256), 0, stream>>>(
            Wt, Abf[i], M, Mpad_[i], K2, C, Cp_[i], Kp_[i], C * K2);

        int MWi = kMW[i];
        int nBlkM = Mpad_[i] / (64 * MWi);
        int totalBlk = (N / BNT) * nBlkM;          // % 8 == 0 for all layers
        int lgM = __builtin_ctz(nBlkM);
        if (MWi == 2)
            sconv_mfma_kernel<2><<<dim3(totalBlk), dim3(256), 0, stream>>>(
                Abf[i], bias, c.s1, c.s2, c.C1, C, Cp_[i], H, W, c.up,
                K2, k, st, lWo, lHo, c.delta,
                c.Y, M, Kp_[i], N, lgM);
        else
            sconv_mfma_kernel<1><<<dim3(totalBlk), dim3(256), 0, stream>>>(
                Abf[i], bias, c.s1, c.s2, c.C1, C, Cp_[i], H, W, c.up,
                K2, k, st, lWo, lHo, c.delta,
                c.Y, M, Kp_[i], N, lgM);

        bn_stats_part_kernel<<<dim3(M, SPLIT), dim3(256), 0, stream>>>(
            c.Y, part, M, HW, B);
        int total = B * M * HW;
        bn_apply_kernel<<<dim3(total / 256), dim3(256), 0, stream>>>(
            c.Y, part, gam, bet, M, HW, B, total);
    }
}

// Round 13
// 1278.832 us; speedup vs baseline: 1.9788x; 1.0447x over previous
//
#include <hip/hip_runtime.h>
#include <cstddef>
#include <cstdint>

#define PI_F 3.14159265358979323846f

typedef __attribute__((ext_vector_type(8))) short short8;   // 8 bf16 = 4 VGPRs
typedef __attribute__((ext_vector_type(4))) float floatx4;  // MFMA acc

__device__ __forceinline__ short f2bf(float f) {
    union { float f; unsigned u; } v; v.f = f;
    unsigned r = v.u + 0x7FFFu + ((v.u >> 16) & 1u);   // RNE
    return (short)(r >> 16);
}

// ---------------------------------------------------------------------------
// Weight transpose+convert: Abf[m][k'] = bf16(A[m][c*K2 + tap]), k' = tap*Cp+c
// ---------------------------------------------------------------------------
__global__ __launch_bounds__(256) void wtrans_kernel(
    const float* __restrict__ A, short* __restrict__ Abf,
    int M, int Mpad, int K2, int C, int Cp, int Kp, int Korig)
{
    int idx = blockIdx.x * 256 + threadIdx.x;
    if (idx >= Mpad * Kp) return;
    int m = idx / Kp;
    int k = idx - m * Kp;
    int tap = (unsigned)k / (unsigned)Cp;
    int c   = k - tap * Cp;
    float v = 0.f;
    if (m < M && tap < K2 && c < C) v = A[(size_t)m * Korig + c * K2 + tap];
    Abf[idx] = f2bf(v);
}

// ---------------------------------------------------------------------------
// Fused spherical-conv GEMM, bf16 MFMA, channel-innermost K.
// ROUND-13: r12 structure with two fixes:
//  * MW=2 ONLY for L6 (512 blocks = 2/CU). r12 counters: MW=2 on L5 gave 256
//    blocks = 1 block/CU -> occupancy 11%, VALUBusy 16.6% (latency cliff);
//    L3/L31 got 128 blocks = half the CUs idle. Rule: MW=2 needs >=2 blk/CU.
//  * BN partial stats in the epilogue via UNIQUE per-(m,nblk) slots (plain
//    stores — r10 proved contended cross-XCD atomics are poison; uncontended
//    stores are free). Deletes the separate 63MB-read stats pass.
// ---------------------------------------------------------------------------
#define BNT 64
#define BKT 32
#define LDK 40

template<int MW>
__global__ __launch_bounds__(256) void sconv_mfma_kernel(
    const short* __restrict__ Abf, const float* __restrict__ bias,
    const float* __restrict__ src1, const float* __restrict__ src2,
    float2* __restrict__ part, int nBlkN,
    int C1, int Ctot, int Cp, int H, int W, int up1,
    int K2, int ksz, int stride, int lWo, int lHo, float delta,
    float* __restrict__ Y, int M, int Kp, int N, int lgM)
{
    __shared__ short Bs[BNT][LDK];
    __shared__ float4 tab[64];          // max nHo*K2 = 49 over all layers

    const int tid = threadIdx.x;
    // ---- XCD swizzle (total % 8 == 0 for all layers) ----
    const int total = gridDim.x;
    const int pid = blockIdx.x;
    const int logical = (pid & 7) * (total >> 3) + (pid >> 3);
    const int m0 = (logical & ((1 << lgM) - 1)) * (MW * 64);
    const int nblk = logical >> lgM;
    const int n0 = nblk * BNT;

    const int Wo  = 1 << lWo;
    const int Ho  = 1 << lHo;
    const int HW  = 1 << (lWo + lHo);

    // ---- per-block grid table: (hoLocal, tap) -> {fr, dcol, r0i, r1i} ----
    const int nHo  = (lWo >= 6) ? 1 : (BNT >> lWo);
    const int nEnt = nHo * K2;
    const int hoBase = (n0 >> lWo) & (Ho - 1);
    if (tid < nEnt) {
        int hoL = tid / K2;
        int i   = tid - hoL * K2;
        int ho_g = hoBase + hoL;
        int jy = i / ksz, jx = i - jy * ksz;
        float halfk = (ksz - 1) * 0.5f;
        float yy = tanf(delta / (float)ksz * ((float)jy - halfk));
        float xx = tanf(delta / (float)ksz * ((float)jx - halfk));
        float rho = sqrtf(xx * xx + yy * yy);
        float rho_s = (rho == 0.f) ? 1.f : rho;
        float nu = atanf(rho);
        float lat0 = PI_F * 0.5f - ((float)(ho_g * stride) + 0.5f) * (PI_F / (float)H);
        float sl = sinf(lat0), cl = cosf(lat0);
        float sn = sinf(nu),  cn = cosf(nu);
        float arg = cn * sl + (yy / rho_s) * sn * cl;
        arg = fminf(1.f, fmaxf(-1.f, arg));
        float lat = asinf(arg);
        float dlon = atan2f(xx * sn, rho * cl * cn - yy * sl * sn);
        float row = (PI_F * 0.5f - lat) / PI_F * (float)H - 0.5f;
        float dcol = dlon / (2.f * PI_F) * (float)W;
        float r0f = floorf(row);
        float fr = row - r0f;
        int r0 = (int)r0f;
        int r0i = min(max(r0, 0), H - 1);
        int r1i = min(max(r0 + 1, 0), H - 1);
        tab[tid] = make_float4(fr, dcol, __int_as_float(r0i), __int_as_float(r1i));
    }

    // ---- B staging geometry (lane nn = coalesced wo) ----
    const int nn    = tid & 63;
    const int kslot = tid >> 6;         // wave-uniform
    const int n_s  = n0 + nn;
    const int wo_s = n_s & (Wo - 1);
    const int hoL_s = nn >> lWo;
    const int b_s  = n_s >> (lWo + lHo);   // block-uniform (HW multiple of 64)
    const int tabBase = hoL_s * K2;
    const float wo_px = (float)(wo_s * stride);
    const int Hs = H >> up1, Ws = W >> up1;
    const int plane1 = Hs * Ws;
    const int plane2 = H * W;
    const unsigned boff1 = (unsigned)(b_s * C1 * plane1);
    const unsigned boff2 = (unsigned)(b_s * (Ctot - C1) * plane2);

    // ---- (tap, cb) iteration state: chunk = one tap, 8 channels ----
    const bool smallC = (Cp < 32);      // layer 1 only (Cp=8)
    int tap = smallC ? kslot : 0;
    int cb  = smallC ? 0 : kslot * 8;
    const int dtap = smallC ? (32 / Cp) : 0;

    // ---- wave/lane decomposition: wave tile = MW*16 rows x 64 cols ----
    const int wave = tid >> 6;
    const int wrow = wave * (MW * 16);
    const int lane = tid & 63;
    const int l16  = lane & 15;
    const int quad = lane >> 4;

    const short* pA[MW];
#pragma unroll
    for (int i = 0; i < MW; i++)
        pA[i] = Abf + (size_t)(m0 + wrow + i * 16 + l16) * Kp + quad * 8;

    floatx4 acc[MW][4];
#pragma unroll
    for (int i = 0; i < MW; i++)
#pragma unroll
        for (int j = 0; j < 4; j++)
            acc[i][j] = (floatx4){0.f, 0.f, 0.f, 0.f};

    __syncthreads();   // table ready

    for (int k0 = 0; k0 < Kp; k0 += BKT) {
        // ---- B tile: one tap, 8 channels (inline gather) ----
        {
            const int tapc = min(tap, K2 - 1);       // clamp for L1 pad region
            const float4 e = tab[tabBase + tapc];
            const float fr = e.x;
            const float col = wo_px + e.y;
            const int r0i = __float_as_int(e.z);
            const int r1i = __float_as_int(e.w);
            const float cf = floorf(col);
            const float fc = col - cf;
            const int c0 = ((int)cf) & (W - 1);
            const int c1 = (c0 + 1) & (W - 1);
            const float w00 = (1.f - fr) * (1.f - fc);
            const float w01 = (1.f - fr) * fc;
            const float w10 = fr * (1.f - fc);
            const float w11 = fr * fc;

            const float* src; unsigned i00, i01, i10, i11, plane;
            if (cb < C1) {               // wave-uniform branch
                const int ra = (r0i >> up1) * Ws, rb = (r1i >> up1) * Ws;
                const int ca = c0 >> up1, cx = c1 >> up1;
                const unsigned base = boff1 + (unsigned)cb * plane1;
                i00 = base + ra + ca; i01 = base + ra + cx;
                i10 = base + rb + ca; i11 = base + rb + cx;
                plane = plane1; src = src1;
            } else {
                const int ra = r0i * W, rb = r1i * W;
                const unsigned base = boff2 + (unsigned)(cb - C1) * plane2;
                i00 = base + ra + c0; i01 = base + ra + c1;
                i10 = base + rb + c0; i11 = base + rb + c1;
                plane = plane2; src = src2;
            }
            short t8[8];
#pragma unroll
            for (int j = 0; j < 8; j++) {
                float v = 0.f;
                if (cb + j < Ctot) {     // guard BEFORE loads (L1: src2 null)
                    v = w00 * src[i00] + w01 * src[i01]
                      + w10 * src[i10] + w11 * src[i11];
                }
                t8[j] = f2bf(v);
                i00 += plane; i01 += plane; i10 += plane; i11 += plane;
            }
            *(short8*)&Bs[nn][kslot * 8] = *(short8*)&t8[0];
        }
        __syncthreads();

        short8 af[MW];
#pragma unroll
        for (int i = 0; i < MW; i++)
            af[i] = *(const short8*)(pA[i] + k0);
        short8 bf[4];
#pragma unroll
        for (int j = 0; j < 4; j++)
            bf[j] = *(const short8*)&Bs[j * 16 + l16][quad * 8];
#pragma unroll
        for (int i = 0; i < MW; i++)
#pragma unroll
            for (int j = 0; j < 4; j++)
                acc[i][j] = __builtin_amdgcn_mfma_f32_16x16x32_bf16(
                    af[i], bf[j], acc[i][j], 0, 0, 0);
        __syncthreads();

        // advance (tap, cb)
        if (smallC) { tap += dtap; }
        else { cb += 32; if (cb >= Cp) { cb -= Cp; tap++; } }
    }

    // ---- epilogue: store + BN partials to UNIQUE slots (no atomics) ----
    // C/D layout col=lane&15, row=quad*4+reg. Per (i,rr): sum over 4 j-cols
    // + 16 lanes (shfl_xor) = all 64 block cols for channel m; lane l16==0
    // stores part[m*nBlkN + nblk]. Every (m<M, nblk) slot is written by
    // exactly one block -> finalize needs no zero-init.
#pragma unroll
    for (int i = 0; i < MW; i++) {
#pragma unroll
        for (int rr = 0; rr < 4; rr++) {
            const int m = m0 + wrow + i * 16 + quad * 4 + rr;
            const bool mv = (m < M);
            const float bv = mv ? bias[m] : 0.f;
            float s = 0.f, q = 0.f;
#pragma unroll
            for (int j = 0; j < 4; j++) {
                const int n = n0 + j * 16 + l16;
                const float v = acc[i][j][rr] + bv;
                s += v; q += v * v;
                if (mv) {
                    const int wo = n & (Wo - 1);
                    const int r  = n >> lWo;
                    const int ho = r & (Ho - 1);
                    const int b_ = r >> lHo;
                    Y[((size_t)b_ * M + m) * HW + (ho << lWo) + wo] = v;
                }
            }
#pragma unroll
            for (int mask = 1; mask < 16; mask <<= 1) {
                s += __shfl_xor(s, mask);
                q += __shfl_xor(q, mask);
            }
            if (mv && l16 == 0)
                part[(size_t)m * nBlkN + nblk] = make_float2(s, q);
        }
    }
}

// ---------------------------------------------------------------------------
// BN finalize: one block per channel; reduce nBlkN partial slots -> {sc, sf}.
// ---------------------------------------------------------------------------
__global__ __launch_bounds__(256) void bn_finalize_kernel(
    const float2* __restrict__ part, float2* __restrict__ scSf,
    const float* __restrict__ g, const float* __restrict__ bb,
    int nBlkN, int Nt)
{
    int c = blockIdx.x;
    int tid = threadIdx.x;
    double s = 0.0, q = 0.0;
    for (int k = tid; k < nBlkN; k += 256) {
        float2 p = part[(size_t)c * nBlkN + k];
        s += p.x; q += p.y;
    }
    __shared__ double sh_s[256], sh_q[256];
    sh_s[tid] = s; sh_q[tid] = q;
    __syncthreads();
    for (int off = 128; off > 0; off >>= 1) {
        if (tid < off) { sh_s[tid] += sh_s[tid + off]; sh_q[tid] += sh_q[tid + off]; }
        __syncthreads();
    }
    if (tid == 0) {
        double mean = sh_s[0] / Nt;
        double var = sh_q[0] / Nt - mean * mean;
        if (var < 0.0) var = 0.0;
        float sc = g[c] / sqrtf((float)var + 1e-5f);
        scSf[c] = make_float2(sc, bb[c] - (float)mean * sc);
    }
}

// Normalize + ReLU using finalized per-channel {sc, sf}.
__global__ __launch_bounds__(256) void bn_apply_kernel(
    float* __restrict__ Y, const float2* __restrict__ scSf,
    int Co, int HW, int total)
{
    int idx = blockIdx.x * 256 + threadIdx.x;
    if (idx >= total) return;
    int c = (idx / HW) % Co;
    float2 s = scSf[c];
    float v = Y[idx] * s.x + s.y;
    Y[idx] = v > 0.f ? v : 0.f;
}

// ---------------------------------------------------------------------------
// Host orchestration. Workspace ~39 MB: part 4MB + scSf 2KB + activations
// 29.4MB + Abf 5.1MB. Scratch Q reuse by lifetime: x1=Q (L1-2), x3=Q (L3-4),
// x4=Q (L5-6), x41=Q+512K (L6-7), x5=Q+1M (L7-8).
// ---------------------------------------------------------------------------
extern "C" void kernel_launch(void* const* d_in, const int* in_sizes, int n_in,
                              void* d_out, int out_size, void* d_ws, size_t ws_size,
                              hipStream_t stream)
{
    const int B = 4;
    char* ws = (char*)d_ws;
    size_t off = 0;
    auto allocb = [&](size_t bytes) -> void* {
        void* p = ws + off;
        off = (off + bytes + 255) & ~(size_t)255;
        return p;
    };

    float2* part = (float2*)allocb((size_t)256 * 2048 * sizeof(float2));
    float2* scSf = (float2*)allocb(256 * sizeof(float2));
    float* x2  = (float*)allocb((size_t)B * 64  * 64 * 128 * 4);
    float* x31 = (float*)allocb((size_t)B * 128 * 32 * 64 * 4);
    float* Q   = (float*)allocb((size_t)B * 32  * 128 * 256 * 4);
    float* x1  = Q;
    float* x3  = Q;
    float* x4  = Q;
    float* x41 = Q + (size_t)B * 256 * 16 * 32;
    float* x5  = Q + 2 * (size_t)B * 256 * 16 * 32;

    //                      1     2     3    31     4    41     5     6
    static const int kH[8]  = {256, 128,  64,  32,  32,  16,  32,  64};
    static const int kW[8]  = {512, 256, 128,  64,  64,  32,  64, 128};
    static const int kK[8]  = {  7,   5,   5,   3,   3,   3,   3,   3};
    static const int kSt[8] = {  2,   2,   2,   1,   2,   1,   1,   1};
    static const int kC[8]  = {  6,  32,  64, 128, 128, 256, 384, 320};
    static const int kM[8]  = { 32,  64, 128, 128, 256, 256, 256, 128};
    // MW=2 only where the grid keeps >=2 blocks/CU (r12: L5 at 1 blk/CU ->
    // occupancy 11%; L3/L31 at 128 blocks -> half the CUs idle):
    static const int kMW[8] = {  1,   1,   1,   1,   1,   1,   1,   2};

    int Cp_[8], Kp_[8], Mpad_[8];
    short* Abf[8];
    for (int i = 0; i < 8; i++) {
        int K2 = kK[i] * kK[i];
        int Cp = (kC[i] < 8) ? 8 : kC[i];
        int Kp = (K2 * Cp + 31) & ~31;
        int Mpad = (kM[i] + 63) & ~63;
        Cp_[i] = Cp; Kp_[i] = Kp; Mpad_[i] = Mpad;
        Abf[i] = (short*)allocb((size_t)Mpad * Kp * sizeof(short));
    }
    (void)ws_size; (void)in_sizes; (void)n_in; (void)out_size;

    struct LCfg { const float *s1, *s2; int C1, up; float delta; int widx; float* Y; };
    const float* input = (const float*)d_in[0];
    LCfg L[8] = {
        { input, nullptr,   6, 0, PI_F / 32.f,  1, x1  },
        { x1,    nullptr,  32, 0, PI_F / 16.f,  5, x2  },
        { x2,    nullptr,  64, 0, PI_F / 4.f,   9, x3  },
        { x3,    nullptr, 128, 0, PI_F / 4.f,  13, x31 },
        { x31,   nullptr, 128, 0, PI_F / 2.f,  17, x4  },
        { x4,    nullptr, 256, 0, PI_F / 2.f,  21, x41 },
        { x41,   x31,     256, 1, PI_F / 4.f,  25, x5  },
        { x5,    x2,      256, 1, PI_F / 8.f,  29, (float*)d_out },
    };

    for (int i = 0; i < 8; i++) {
        const LCfg& c = L[i];
        int H = kH[i], W = kW[i], k = kK[i], st = kSt[i];
        int Ho = H / st, Wo = W / st;
        int K2 = k * k;
        int C  = kC[i], M = kM[i];
        int HW = Ho * Wo;
        int N  = B * HW;
        int lWo = __builtin_ctz(Wo), lHo = __builtin_ctz(Ho);
        const float* Wt   = (const float*)d_in[c.widx];
        const float* bias = (const float*)d_in[c.widx + 1];
        const float* gam  = (const float*)d_in[c.widx + 2];
        const float* bet  = (const float*)d_in[c.widx + 3];

        int tn = Mpad_[i] * Kp_[i];
        wtrans_kernel<<<dim3((tn + 255) / 256), dim3(256), 0, stream>>>(
            Wt, Abf[i], M, Mpad_[i], K2, C, Cp_[i], Kp_[i], C * K2);

        int MWi = kMW[i];
        int nBlkM = Mpad_[i] / (64 * MWi);
        int nBlkN = N / BNT;
        int totalBlk = nBlkN * nBlkM;              // % 8 == 0 for all layers
        int lgM = __builtin_ctz(nBlkM);
        if (MWi == 2)
            sconv_mfma_kernel<2><<<dim3(totalBlk), dim3(256), 0, stream>>>(
                Abf[i], bias, c.s1, c.s2, part, nBlkN,
                c.C1, C, Cp_[i], H, W, c.up,
                K2, k, st, lWo, lHo, c.delta,
                c.Y, M, Kp_[i], N, lgM);
        else
            sconv_mfma_kernel<1><<<dim3(totalBlk), dim3(256), 0, stream>>>(
                Abf[i], bias, c.s1, c.s2, part, nBlkN,
                c.C1, C, Cp_[i], H, W, c.up,
                K2, k, st, lWo, lHo, c.delta,
                c.Y, M, Kp_[i], N, lgM);

        bn_finalize_kernel<<<dim3(M), dim3(256), 0, stream>>>(
            part, scSf, gam, bet, nBlkN, N);
        int total = B * M * HW;
        bn_apply_kernel<<<dim3(total / 256), dim3(256), 0, stream>>>(
            c.Y, scSf, M, HW, total);
    }
}

// Round 14
// 952.718 us; speedup vs baseline: 2.6561x; 1.3423x over previous
//
#include <hip/hip_runtime.h>
#include <cstddef>
#include <cstdint>

#define PI_F 3.14159265358979323846f

typedef __attribute__((ext_vector_type(8))) short short8;   // 8 bf16 = 4 VGPRs
typedef __attribute__((ext_vector_type(4))) float floatx4;  // MFMA acc

__device__ __forceinline__ short f2bf(float f) {
    union { float f; unsigned u; } v; v.f = f;
    unsigned r = v.u + 0x7FFFu + ((v.u >> 16) & 1u);   // RNE
    return (short)(r >> 16);
}

// ---------------------------------------------------------------------------
// Weight transpose+convert: Abf[m][k'] = bf16(A[m][c*K2 + tap]), k' = tap*Cp+c
// ---------------------------------------------------------------------------
__global__ __launch_bounds__(256) void wtrans_kernel(
    const float* __restrict__ A, short* __restrict__ Abf,
    int M, int Mpad, int K2, int C, int Cp, int Kp, int Korig)
{
    int idx = blockIdx.x * 256 + threadIdx.x;
    if (idx >= Mpad * Kp) return;
    int m = idx / Kp;
    int k = idx - m * Kp;
    int tap = (unsigned)k / (unsigned)Cp;
    int c   = k - tap * Cp;
    float v = 0.f;
    if (m < M && tap < K2 && c < C) v = A[(size_t)m * Korig + c * K2 + tap];
    Abf[idx] = f2bf(v);
}

__global__ __launch_bounds__(256) void zero_kernel(float* __restrict__ p, int n)
{
    int i = blockIdx.x * 256 + threadIdx.x;
    if (i < n) p[i] = 0.f;
}

// ---------------------------------------------------------------------------
// Fused spherical-conv GEMM, bf16 MFMA, channel-innermost K.
// ROUND-14: r13 + SPLIT-K for grid-limited layers. r13 counters: L5 at 512
// blocks = 2 blk/CU -> occ 21.6%, VALU 31.6% (co-residency ceiling); L4/L41
// at 128 blocks leave half the CUs idle. SK slices the K-loop; slices
// accumulate into zero-initialized Y via native fp32 unsafeAtomicAdd (2-4
// adds/element spread over MBs — benign, unlike r10's 262K-on-1KB).
// kslice bits sit between m and n in the swizzled decode -> all slices of an
// n-block share an XCD (gather L2 reuse preserved).
// Conv BIAS IS DROPPED EVERYWHERE: train-mode BN subtracts the per-channel
// mean, so a per-channel constant shift cancels exactly.
// MW widens the m-tile (halves gather redundancy); safe only when the
// resulting grid keeps >=2 blocks/CU (r12 lesson) — SK restores that for L5.
// ---------------------------------------------------------------------------
#define BNT 64
#define BKT 32
#define LDK 40

template<int MW, int SK>
__global__ __launch_bounds__(256) void sconv_mfma_kernel(
    const short* __restrict__ Abf,
    const float* __restrict__ src1, const float* __restrict__ src2,
    float2* __restrict__ part, int nBlkN,
    int C1, int Ctot, int Cp, int H, int W, int up1,
    int K2, int ksz, int stride, int lWo, int lHo, float delta,
    float* __restrict__ Y, int M, int Kp, int N, int lgM)
{
    __shared__ short Bs[BNT][LDK];
    __shared__ float4 tab[64];          // max nHo*K2 = 49 over all layers

    constexpr int LGSK = (SK == 1) ? 0 : ((SK == 2) ? 1 : 2);

    const int tid = threadIdx.x;
    // ---- XCD swizzle (total % 8 == 0 for all layers) ----
    const int total = gridDim.x;
    const int pid = blockIdx.x;
    const int logical = (pid & 7) * (total >> 3) + (pid >> 3);
    const int mblk = logical & ((1 << lgM) - 1);
    const int rest = logical >> lgM;
    const int kslice = rest & (SK - 1);
    const int nblk = rest >> LGSK;
    const int m0 = mblk * (MW * 64);
    const int n0 = nblk * BNT;

    const int Wo  = 1 << lWo;
    const int Ho  = 1 << lHo;
    const int HW  = 1 << (lWo + lHo);

    // ---- per-block grid table: (hoLocal, tap) -> {fr, dcol, r0i, r1i} ----
    const int nHo  = (lWo >= 6) ? 1 : (BNT >> lWo);
    const int nEnt = nHo * K2;
    const int hoBase = (n0 >> lWo) & (Ho - 1);
    if (tid < nEnt) {
        int hoL = tid / K2;
        int i   = tid - hoL * K2;
        int ho_g = hoBase + hoL;
        int jy = i / ksz, jx = i - jy * ksz;
        float halfk = (ksz - 1) * 0.5f;
        float yy = tanf(delta / (float)ksz * ((float)jy - halfk));
        float xx = tanf(delta / (float)ksz * ((float)jx - halfk));
        float rho = sqrtf(xx * xx + yy * yy);
        float rho_s = (rho == 0.f) ? 1.f : rho;
        float nu = atanf(rho);
        float lat0 = PI_F * 0.5f - ((float)(ho_g * stride) + 0.5f) * (PI_F / (float)H);
        float sl = sinf(lat0), cl = cosf(lat0);
        float sn = sinf(nu),  cn = cosf(nu);
        float arg = cn * sl + (yy / rho_s) * sn * cl;
        arg = fminf(1.f, fmaxf(-1.f, arg));
        float lat = asinf(arg);
        float dlon = atan2f(xx * sn, rho * cl * cn - yy * sl * sn);
        float row = (PI_F * 0.5f - lat) / PI_F * (float)H - 0.5f;
        float dcol = dlon / (2.f * PI_F) * (float)W;
        float r0f = floorf(row);
        float fr = row - r0f;
        int r0 = (int)r0f;
        int r0i = min(max(r0, 0), H - 1);
        int r1i = min(max(r0 + 1, 0), H - 1);
        tab[tid] = make_float4(fr, dcol, __int_as_float(r0i), __int_as_float(r1i));
    }

    // ---- B staging geometry (lane nn = coalesced wo) ----
    const int nn    = tid & 63;
    const int kslot = tid >> 6;         // wave-uniform
    const int n_s  = n0 + nn;
    const int wo_s = n_s & (Wo - 1);
    const int hoL_s = nn >> lWo;
    const int b_s  = n_s >> (lWo + lHo);   // block-uniform (HW multiple of 64)
    const int tabBase = hoL_s * K2;
    const float wo_px = (float)(wo_s * stride);
    const int Hs = H >> up1, Ws = W >> up1;
    const int plane1 = Hs * Ws;
    const int plane2 = H * W;
    const unsigned boff1 = (unsigned)(b_s * C1 * plane1);
    const unsigned boff2 = (unsigned)(b_s * (Ctot - C1) * plane2);

    // ---- K-slice bounds + (tap, cb) init at slice start ----
    const int Tper = (Kp / BKT) / SK;
    const int t0 = kslice * Tper;
    const bool smallC = (Cp < 32);      // layer 1 only (Cp=8, never split)
    int tap, cb;
    if (smallC) { tap = kslot; cb = 0; }
    else {
        int prog = t0 * BKT;            // Cp % 32 == 0 for all split layers
        tap = prog / Cp;
        cb  = prog - tap * Cp + kslot * 8;
    }
    const int dtap = smallC ? (32 / Cp) : 0;

    // ---- wave/lane decomposition: wave tile = MW*16 rows x 64 cols ----
    const int wave = tid >> 6;
    const int wrow = wave * (MW * 16);
    const int lane = tid & 63;
    const int l16  = lane & 15;
    const int quad = lane >> 4;

    const short* pA[MW];
#pragma unroll
    for (int i = 0; i < MW; i++)
        pA[i] = Abf + (size_t)(m0 + wrow + i * 16 + l16) * Kp + quad * 8;

    floatx4 acc[MW][4];
#pragma unroll
    for (int i = 0; i < MW; i++)
#pragma unroll
        for (int j = 0; j < 4; j++)
            acc[i][j] = (floatx4){0.f, 0.f, 0.f, 0.f};

    __syncthreads();   // table ready

    for (int t = t0; t < t0 + Tper; t++) {
        const int k0 = t * BKT;
        // ---- B tile: one tap, 8 channels (inline gather) ----
        {
            const int tapc = min(tap, K2 - 1);       // clamp for L1 pad region
            const float4 e = tab[tabBase + tapc];
            const float fr = e.x;
            const float col = wo_px + e.y;
            const int r0i = __float_as_int(e.z);
            const int r1i = __float_as_int(e.w);
            const float cf = floorf(col);
            const float fc = col - cf;
            const int c0 = ((int)cf) & (W - 1);
            const int c1 = (c0 + 1) & (W - 1);
            const float w00 = (1.f - fr) * (1.f - fc);
            const float w01 = (1.f - fr) * fc;
            const float w10 = fr * (1.f - fc);
            const float w11 = fr * fc;

            const float* src; unsigned i00, i01, i10, i11, plane;
            if (cb < C1) {               // wave-uniform branch
                const int ra = (r0i >> up1) * Ws, rb = (r1i >> up1) * Ws;
                const int ca = c0 >> up1, cx = c1 >> up1;
                const unsigned base = boff1 + (unsigned)cb * plane1;
                i00 = base + ra + ca; i01 = base + ra + cx;
                i10 = base + rb + ca; i11 = base + rb + cx;
                plane = plane1; src = src1;
            } else {
                const int ra = r0i * W, rb = r1i * W;
                const unsigned base = boff2 + (unsigned)(cb - C1) * plane2;
                i00 = base + ra + c0; i01 = base + ra + c1;
                i10 = base + rb + c0; i11 = base + rb + c1;
                plane = plane2; src = src2;
            }
            short t8[8];
#pragma unroll
            for (int j = 0; j < 8; j++) {
                float v = 0.f;
                if (cb + j < Ctot) {     // guard BEFORE loads (L1: src2 null)
                    v = w00 * src[i00] + w01 * src[i01]
                      + w10 * src[i10] + w11 * src[i11];
                }
                t8[j] = f2bf(v);
                i00 += plane; i01 += plane; i10 += plane; i11 += plane;
            }
            *(short8*)&Bs[nn][kslot * 8] = *(short8*)&t8[0];
        }
        __syncthreads();

        short8 af[MW];
#pragma unroll
        for (int i = 0; i < MW; i++)
            af[i] = *(const short8*)(pA[i] + k0);
        short8 bf[4];
#pragma unroll
        for (int j = 0; j < 4; j++)
            bf[j] = *(const short8*)&Bs[j * 16 + l16][quad * 8];
#pragma unroll
        for (int i = 0; i < MW; i++)
#pragma unroll
            for (int j = 0; j < 4; j++)
                acc[i][j] = __builtin_amdgcn_mfma_f32_16x16x32_bf16(
                    af[i], bf[j], acc[i][j], 0, 0, 0);
        __syncthreads();

        // advance (tap, cb)
        if (smallC) { tap += dtap; }
        else { cb += 32; if (cb >= Cp) { cb -= Cp; tap++; } }
    }

    // ---- epilogue (C/D layout col=lane&15, row=quad*4+reg) ----
    if (SK == 1) {
        // plain store + BN partials to UNIQUE per-(m,nblk) slots (no atomics)
#pragma unroll
        for (int i = 0; i < MW; i++) {
#pragma unroll
            for (int rr = 0; rr < 4; rr++) {
                const int m = m0 + wrow + i * 16 + quad * 4 + rr;
                const bool mv = (m < M);
                float s = 0.f, q = 0.f;
#pragma unroll
                for (int j = 0; j < 4; j++) {
                    const int n = n0 + j * 16 + l16;
                    const float v = acc[i][j][rr];
                    s += v; q += v * v;
                    if (mv) {
                        const int wo = n & (Wo - 1);
                        const int r  = n >> lWo;
                        const int ho = r & (Ho - 1);
                        const int b_ = r >> lHo;
                        Y[((size_t)b_ * M + m) * HW + (ho << lWo) + wo] = v;
                    }
                }
#pragma unroll
                for (int mask = 1; mask < 16; mask <<= 1) {
                    s += __shfl_xor(s, mask);
                    q += __shfl_xor(q, mask);
                }
                if (mv && l16 == 0)
                    part[(size_t)m * nBlkN + nblk] = make_float2(s, q);
            }
        }
    } else {
        // split-K: accumulate into zero-initialized Y (native f32 atomic add)
#pragma unroll
        for (int i = 0; i < MW; i++) {
#pragma unroll
            for (int j = 0; j < 4; j++) {
                const int n = n0 + j * 16 + l16;
                const int wo = n & (Wo - 1);
                const int r  = n >> lWo;
                const int ho = r & (Ho - 1);
                const int b_ = r >> lHo;
#pragma unroll
                for (int rr = 0; rr < 4; rr++) {
                    const int m = m0 + wrow + i * 16 + quad * 4 + rr;
                    if (m < M)
                        unsafeAtomicAdd(
                            &Y[((size_t)b_ * M + m) * HW + (ho << lWo) + wo],
                            acc[i][j][rr]);
                }
            }
        }
    }
}

// ---------------------------------------------------------------------------
// BN stats for split-K layers: grid (Co, 8), float partials -> part[c*8+sp].
// ---------------------------------------------------------------------------
__global__ __launch_bounds__(256) void bn_stats8_kernel(
    const float* __restrict__ Y, float2* __restrict__ part,
    int Co, int HW, int B)
{
    int co = blockIdx.x;
    int sp = blockIdx.y;
    int tid = threadIdx.x;
    int Nt = B * HW;
    int len = Nt >> 3;                  // Nt multiple of 8 (HW >= 512)
    int start = sp * len, end = start + len;
    float s = 0.f, q = 0.f;
    for (int idx = start + tid; idx < end; idx += 256) {
        int b = idx / HW; int o = idx - b * HW;
        float v = Y[((size_t)b * Co + co) * HW + o];
        s += v; q += v * v;
    }
    __shared__ float sh_s[256], sh_q[256];
    sh_s[tid] = s; sh_q[tid] = q;
    __syncthreads();
    for (int off = 128; off > 0; off >>= 1) {
        if (tid < off) { sh_s[tid] += sh_s[tid + off]; sh_q[tid] += sh_q[tid + off]; }
        __syncthreads();
    }
    if (tid == 0)
        part[co * 8 + sp] = make_float2(sh_s[0], sh_q[0]);
}

// ---------------------------------------------------------------------------
// BN finalize: one block per channel; reduce nBlkN partial slots -> {sc, sf}.
// ---------------------------------------------------------------------------
__global__ __launch_bounds__(256) void bn_finalize_kernel(
    const float2* __restrict__ part, float2* __restrict__ scSf,
    const float* __restrict__ g, const float* __restrict__ bb,
    int nBlkN, int Nt)
{
    int c = blockIdx.x;
    int tid = threadIdx.x;
    double s = 0.0, q = 0.0;
    for (int k = tid; k < nBlkN; k += 256) {
        float2 p = part[(size_t)c * nBlkN + k];
        s += p.x; q += p.y;
    }
    __shared__ double sh_s[256], sh_q[256];
    sh_s[tid] = s; sh_q[tid] = q;
    __syncthreads();
    for (int off = 128; off > 0; off >>= 1) {
        if (tid < off) { sh_s[tid] += sh_s[tid + off]; sh_q[tid] += sh_q[tid + off]; }
        __syncthreads();
    }
    if (tid == 0) {
        double mean = sh_s[0] / Nt;
        double var = sh_q[0] / Nt - mean * mean;
        if (var < 0.0) var = 0.0;
        float sc = g[c] / sqrtf((float)var + 1e-5f);
        scSf[c] = make_float2(sc, bb[c] - (float)mean * sc);
    }
}

// Normalize + ReLU using finalized per-channel {sc, sf}.
__global__ __launch_bounds__(256) void bn_apply_kernel(
    float* __restrict__ Y, const float2* __restrict__ scSf,
    int Co, int HW, int total)
{
    int idx = blockIdx.x * 256 + threadIdx.x;
    if (idx >= total) return;
    int c = (idx / HW) % Co;
    float2 s = scSf[c];
    float v = Y[idx] * s.x + s.y;
    Y[idx] = v > 0.f ? v : 0.f;
}

// ---------------------------------------------------------------------------
// Host orchestration. Workspace ~36 MB: part 512KB + scSf 2KB + activations
// 29.4MB + Abf 5.1MB. Scratch Q reuse by lifetime: x1=Q (L1-2), x3=Q (L3-4),
// x4=Q (L5-6), x41=Q+512K (L6-7), x5=Q+1M (L7-8).
// ---------------------------------------------------------------------------
extern "C" void kernel_launch(void* const* d_in, const int* in_sizes, int n_in,
                              void* d_out, int out_size, void* d_ws, size_t ws_size,
                              hipStream_t stream)
{
    const int B = 4;
    char* ws = (char*)d_ws;
    size_t off = 0;
    auto allocb = [&](size_t bytes) -> void* {
        void* p = ws + off;
        off = (off + bytes + 255) & ~(size_t)255;
        return p;
    };

    float2* part = (float2*)allocb((size_t)65536 * sizeof(float2));
    float2* scSf = (float2*)allocb(256 * sizeof(float2));
    float* x2  = (float*)allocb((size_t)B * 64  * 64 * 128 * 4);
    float* x31 = (float*)allocb((size_t)B * 128 * 32 * 64 * 4);
    float* Q   = (float*)allocb((size_t)B * 32  * 128 * 256 * 4);
    float* x1  = Q;
    float* x3  = Q;
    float* x4  = Q;
    float* x41 = Q + (size_t)B * 256 * 16 * 32;
    float* x5  = Q + 2 * (size_t)B * 256 * 16 * 32;

    //                      1     2     3    31     4    41     5     6
    static const int kH[8]  = {256, 128,  64,  32,  32,  16,  32,  64};
    static const int kW[8]  = {512, 256, 128,  64,  64,  32,  64, 128};
    static const int kK[8]  = {  7,   5,   5,   3,   3,   3,   3,   3};
    static const int kSt[8] = {  2,   2,   2,   1,   2,   1,   1,   1};
    static const int kC[8]  = {  6,  32,  64, 128, 128, 256, 384, 320};
    static const int kM[8]  = { 32,  64, 128, 128, 256, 256, 256, 128};
    // Grid tuning (r12/r13 lessons): every conv needs >=512 blocks.
    // MW=2 halves gather redundancy; SK splits K to restore block count.
    static const int kMW[8] = {  1,   1,   1,   1,   1,   1,   2,   2};
    static const int kSK[8] = {  1,   1,   2,   2,   4,   4,   2,   1};

    int Cp_[8], Kp_[8], Mpad_[8];
    short* Abf[8];
    for (int i = 0; i < 8; i++) {
        int K2 = kK[i] * kK[i];
        int Cp = (kC[i] < 8) ? 8 : kC[i];
        int Kp = (K2 * Cp + 31) & ~31;
        int Mpad = (kM[i] + 63) & ~63;
        Cp_[i] = Cp; Kp_[i] = Kp; Mpad_[i] = Mpad;
        Abf[i] = (short*)allocb((size_t)Mpad * Kp * sizeof(short));
    }
    (void)ws_size; (void)in_sizes; (void)n_in; (void)out_size;

    struct LCfg { const float *s1, *s2; int C1, up; float delta; int widx; float* Y; };
    const float* input = (const float*)d_in[0];
    LCfg L[8] = {
        { input, nullptr,   6, 0, PI_F / 32.f,  1, x1  },
        { x1,    nullptr,  32, 0, PI_F / 16.f,  5, x2  },
        { x2,    nullptr,  64, 0, PI_F / 4.f,   9, x3  },
        { x3,    nullptr, 128, 0, PI_F / 4.f,  13, x31 },
        { x31,   nullptr, 128, 0, PI_F / 2.f,  17, x4  },
        { x4,    nullptr, 256, 0, PI_F / 2.f,  21, x41 },
        { x41,   x31,     256, 1, PI_F / 4.f,  25, x5  },
        { x5,    x2,      256, 1, PI_F / 8.f,  29, (float*)d_out },
    };

    for (int i = 0; i < 8; i++) {
        const LCfg& c = L[i];
        int H = kH[i], W = kW[i], k = kK[i], st = kSt[i];
        int Ho = H / st, Wo = W / st;
        int K2 = k * k;
        int C  = kC[i], M = kM[i];
        int HW = Ho * Wo;
        int N  = B * HW;
        int lWo = __builtin_ctz(Wo), lHo = __builtin_ctz(Ho);
        const float* Wt   = (const float*)d_in[c.widx];
        const float* gam  = (const float*)d_in[c.widx + 2];
        const float* bet  = (const float*)d_in[c.widx + 3];
        int total = B * M * HW;

        int tn = Mpad_[i] * Kp_[i];
        wtrans_kernel<<<dim3((tn + 255) / 256), dim3(256), 0, stream>>>(
            Wt, Abf[i], M, Mpad_[i], K2, C, Cp_[i], Kp_[i], C * K2);

        int MWi = kMW[i], SKi = kSK[i];
        int nBlkM = Mpad_[i] / (64 * MWi);
        int nBlkN = N / BNT;
        int totalBlk = nBlkN * nBlkM * SKi;        // % 8 == 0 for all layers
        int lgM = __builtin_ctz(nBlkM);

        if (SKi > 1)
            zero_kernel<<<dim3((total + 255) / 256), dim3(256), 0, stream>>>(
                c.Y, total);

        #define CONV_ARGS Abf[i], c.s1, c.s2, part, nBlkN, \
            c.C1, C, Cp_[i], H, W, c.up, K2, k, st, lWo, lHo, c.delta, \
            c.Y, M, Kp_[i], N, lgM
        if      (MWi == 1 && SKi == 1)
            sconv_mfma_kernel<1,1><<<dim3(totalBlk), dim3(256), 0, stream>>>(CONV_ARGS);
        else if (MWi == 2 && SKi == 1)
            sconv_mfma_kernel<2,1><<<dim3(totalBlk), dim3(256), 0, stream>>>(CONV_ARGS);
        else if (MWi == 1 && SKi == 2)
            sconv_mfma_kernel<1,2><<<dim3(totalBlk), dim3(256), 0, stream>>>(CONV_ARGS);
        else if (MWi == 1 && SKi == 4)
            sconv_mfma_kernel<1,4><<<dim3(totalBlk), dim3(256), 0, stream>>>(CONV_ARGS);
        else
            sconv_mfma_kernel<2,2><<<dim3(totalBlk), dim3(256), 0, stream>>>(CONV_ARGS);
        #undef CONV_ARGS

        int slots;
        if (SKi > 1) {
            bn_stats8_kernel<<<dim3(M, 8), dim3(256), 0, stream>>>(
                c.Y, part, M, HW, B);
            slots = 8;
        } else {
            slots = nBlkN;
        }
        bn_finalize_kernel<<<dim3(M), dim3(256), 0, stream>>>(
            part, scSf, gam, bet, slots, N);
        bn_apply_kernel<<<dim3(total / 256), dim3(256), 0, stream>>>(
            c.Y, scSf, M, HW, total);
    }
}

// Round 15
// 874.953 us; speedup vs baseline: 2.8922x; 1.0889x over previous
//
#include <hip/hip_runtime.h>
#include <cstddef>
#include <cstdint>

#define PI_F 3.14159265358979323846f

typedef __attribute__((ext_vector_type(8))) short short8;   // 8 bf16 = 4 VGPRs
typedef __attribute__((ext_vector_type(4))) float floatx4;  // MFMA acc

__device__ __forceinline__ short f2bf(float f) {
    union { float f; unsigned u; } v; v.f = f;
    unsigned r = v.u + 0x7FFFu + ((v.u >> 16) & 1u);   // RNE
    return (short)(r >> 16);
}

// ---------------------------------------------------------------------------
// Weight transpose+convert: Abf[m][k'] = bf16(A[m][c*K2 + tap]), k' = tap*Cp+c
// ---------------------------------------------------------------------------
__global__ __launch_bounds__(256) void wtrans_kernel(
    const float* __restrict__ A, short* __restrict__ Abf,
    int M, int Mpad, int K2, int C, int Cp, int Kp, int Korig)
{
    int idx = blockIdx.x * 256 + threadIdx.x;
    if (idx >= Mpad * Kp) return;
    int m = idx / Kp;
    int k = idx - m * Kp;
    int tap = (unsigned)k / (unsigned)Cp;
    int c   = k - tap * Cp;
    float v = 0.f;
    if (m < M && tap < K2 && c < C) v = A[(size_t)m * Korig + c * K2 + tap];
    Abf[idx] = f2bf(v);
}

__global__ __launch_bounds__(256) void zero_kernel(float* __restrict__ p, int n)
{
    int i = blockIdx.x * 256 + threadIdx.x;
    if (i < n) p[i] = 0.f;
}

// ---------------------------------------------------------------------------
// Fused spherical-conv GEMM, bf16 MFMA, channel-innermost K.
// ROUND-15: r14 structure, grid re-tune only. r14 counters: L6 (MW=2, 512
// blocks = 2 blk/CU) hit the co-residency ceiling at occ 20.8% / VALU 32.5%
// — same disease SK already cured on L5. New tuning: L6 MW=2+SK=2 (1024
// blocks), L5 MW=2+SK=4 (1024 blocks). Atomic K-slice accumulation into Y is
// r14-proven benign (spread over MBs; kslice bits keep slices of an n-block
// on one XCD so gather L2 reuse holds).
// Conv bias dropped everywhere (BN mean-subtraction cancels it exactly).
// ---------------------------------------------------------------------------
#define BNT 64
#define BKT 32
#define LDK 40

template<int MW, int SK>
__global__ __launch_bounds__(256) void sconv_mfma_kernel(
    const short* __restrict__ Abf,
    const float* __restrict__ src1, const float* __restrict__ src2,
    float2* __restrict__ part, int nBlkN,
    int C1, int Ctot, int Cp, int H, int W, int up1,
    int K2, int ksz, int stride, int lWo, int lHo, float delta,
    float* __restrict__ Y, int M, int Kp, int N, int lgM)
{
    __shared__ short Bs[BNT][LDK];
    __shared__ float4 tab[64];          // max nHo*K2 = 49 over all layers

    constexpr int LGSK = (SK == 1) ? 0 : ((SK == 2) ? 1 : 2);

    const int tid = threadIdx.x;
    // ---- XCD swizzle (total % 8 == 0 for all layers) ----
    const int total = gridDim.x;
    const int pid = blockIdx.x;
    const int logical = (pid & 7) * (total >> 3) + (pid >> 3);
    const int mblk = logical & ((1 << lgM) - 1);
    const int rest = logical >> lgM;
    const int kslice = rest & (SK - 1);
    const int nblk = rest >> LGSK;
    const int m0 = mblk * (MW * 64);
    const int n0 = nblk * BNT;

    const int Wo  = 1 << lWo;
    const int Ho  = 1 << lHo;
    const int HW  = 1 << (lWo + lHo);

    // ---- per-block grid table: (hoLocal, tap) -> {fr, dcol, r0i, r1i} ----
    const int nHo  = (lWo >= 6) ? 1 : (BNT >> lWo);
    const int nEnt = nHo * K2;
    const int hoBase = (n0 >> lWo) & (Ho - 1);
    if (tid < nEnt) {
        int hoL = tid / K2;
        int i   = tid - hoL * K2;
        int ho_g = hoBase + hoL;
        int jy = i / ksz, jx = i - jy * ksz;
        float halfk = (ksz - 1) * 0.5f;
        float yy = tanf(delta / (float)ksz * ((float)jy - halfk));
        float xx = tanf(delta / (float)ksz * ((float)jx - halfk));
        float rho = sqrtf(xx * xx + yy * yy);
        float rho_s = (rho == 0.f) ? 1.f : rho;
        float nu = atanf(rho);
        float lat0 = PI_F * 0.5f - ((float)(ho_g * stride) + 0.5f) * (PI_F / (float)H);
        float sl = sinf(lat0), cl = cosf(lat0);
        float sn = sinf(nu),  cn = cosf(nu);
        float arg = cn * sl + (yy / rho_s) * sn * cl;
        arg = fminf(1.f, fmaxf(-1.f, arg));
        float lat = asinf(arg);
        float dlon = atan2f(xx * sn, rho * cl * cn - yy * sl * sn);
        float row = (PI_F * 0.5f - lat) / PI_F * (float)H - 0.5f;
        float dcol = dlon / (2.f * PI_F) * (float)W;
        float r0f = floorf(row);
        float fr = row - r0f;
        int r0 = (int)r0f;
        int r0i = min(max(r0, 0), H - 1);
        int r1i = min(max(r0 + 1, 0), H - 1);
        tab[tid] = make_float4(fr, dcol, __int_as_float(r0i), __int_as_float(r1i));
    }

    // ---- B staging geometry (lane nn = coalesced wo) ----
    const int nn    = tid & 63;
    const int kslot = tid >> 6;         // wave-uniform
    const int n_s  = n0 + nn;
    const int wo_s = n_s & (Wo - 1);
    const int hoL_s = nn >> lWo;
    const int b_s  = n_s >> (lWo + lHo);   // block-uniform (HW multiple of 64)
    const int tabBase = hoL_s * K2;
    const float wo_px = (float)(wo_s * stride);
    const int Hs = H >> up1, Ws = W >> up1;
    const int plane1 = Hs * Ws;
    const int plane2 = H * W;
    const unsigned boff1 = (unsigned)(b_s * C1 * plane1);
    const unsigned boff2 = (unsigned)(b_s * (Ctot - C1) * plane2);

    // ---- K-slice bounds + (tap, cb) init at slice start ----
    const int Tper = (Kp / BKT) / SK;
    const int t0 = kslice * Tper;
    const bool smallC = (Cp < 32);      // layer 1 only (Cp=8, never split)
    int tap, cb;
    if (smallC) { tap = kslot; cb = 0; }
    else {
        int prog = t0 * BKT;            // Cp % 32 == 0 for all split layers
        tap = prog / Cp;
        cb  = prog - tap * Cp + kslot * 8;
    }
    const int dtap = smallC ? (32 / Cp) : 0;

    // ---- wave/lane decomposition: wave tile = MW*16 rows x 64 cols ----
    const int wave = tid >> 6;
    const int wrow = wave * (MW * 16);
    const int lane = tid & 63;
    const int l16  = lane & 15;
    const int quad = lane >> 4;

    const short* pA[MW];
#pragma unroll
    for (int i = 0; i < MW; i++)
        pA[i] = Abf + (size_t)(m0 + wrow + i * 16 + l16) * Kp + quad * 8;

    floatx4 acc[MW][4];
#pragma unroll
    for (int i = 0; i < MW; i++)
#pragma unroll
        for (int j = 0; j < 4; j++)
            acc[i][j] = (floatx4){0.f, 0.f, 0.f, 0.f};

    __syncthreads();   // table ready

    for (int t = t0; t < t0 + Tper; t++) {
        const int k0 = t * BKT;
        // ---- B tile: one tap, 8 channels (inline gather) ----
        {
            const int tapc = min(tap, K2 - 1);       // clamp for L1 pad region
            const float4 e = tab[tabBase + tapc];
            const float fr = e.x;
            const float col = wo_px + e.y;
            const int r0i = __float_as_int(e.z);
            const int r1i = __float_as_int(e.w);
            const float cf = floorf(col);
            const float fc = col - cf;
            const int c0 = ((int)cf) & (W - 1);
            const int c1 = (c0 + 1) & (W - 1);
            const float w00 = (1.f - fr) * (1.f - fc);
            const float w01 = (1.f - fr) * fc;
            const float w10 = fr * (1.f - fc);
            const float w11 = fr * fc;

            const float* src; unsigned i00, i01, i10, i11, plane;
            if (cb < C1) {               // wave-uniform branch
                const int ra = (r0i >> up1) * Ws, rb = (r1i >> up1) * Ws;
                const int ca = c0 >> up1, cx = c1 >> up1;
                const unsigned base = boff1 + (unsigned)cb * plane1;
                i00 = base + ra + ca; i01 = base + ra + cx;
                i10 = base + rb + ca; i11 = base + rb + cx;
                plane = plane1; src = src1;
            } else {
                const int ra = r0i * W, rb = r1i * W;
                const unsigned base = boff2 + (unsigned)(cb - C1) * plane2;
                i00 = base + ra + c0; i01 = base + ra + c1;
                i10 = base + rb + c0; i11 = base + rb + c1;
                plane = plane2; src = src2;
            }
            short t8[8];
#pragma unroll
            for (int j = 0; j < 8; j++) {
                float v = 0.f;
                if (cb + j < Ctot) {     // guard BEFORE loads (L1: src2 null)
                    v = w00 * src[i00] + w01 * src[i01]
                      + w10 * src[i10] + w11 * src[i11];
                }
                t8[j] = f2bf(v);
                i00 += plane; i01 += plane; i10 += plane; i11 += plane;
            }
            *(short8*)&Bs[nn][kslot * 8] = *(short8*)&t8[0];
        }
        __syncthreads();

        short8 af[MW];
#pragma unroll
        for (int i = 0; i < MW; i++)
            af[i] = *(const short8*)(pA[i] + k0);
        short8 bf[4];
#pragma unroll
        for (int j = 0; j < 4; j++)
            bf[j] = *(const short8*)&Bs[j * 16 + l16][quad * 8];
#pragma unroll
        for (int i = 0; i < MW; i++)
#pragma unroll
            for (int j = 0; j < 4; j++)
                acc[i][j] = __builtin_amdgcn_mfma_f32_16x16x32_bf16(
                    af[i], bf[j], acc[i][j], 0, 0, 0);
        __syncthreads();

        // advance (tap, cb)
        if (smallC) { tap += dtap; }
        else { cb += 32; if (cb >= Cp) { cb -= Cp; tap++; } }
    }

    // ---- epilogue (C/D layout col=lane&15, row=quad*4+reg) ----
    if (SK == 1) {
        // plain store + BN partials to UNIQUE per-(m,nblk) slots (no atomics)
#pragma unroll
        for (int i = 0; i < MW; i++) {
#pragma unroll
            for (int rr = 0; rr < 4; rr++) {
                const int m = m0 + wrow + i * 16 + quad * 4 + rr;
                const bool mv = (m < M);
                float s = 0.f, q = 0.f;
#pragma unroll
                for (int j = 0; j < 4; j++) {
                    const int n = n0 + j * 16 + l16;
                    const float v = acc[i][j][rr];
                    s += v; q += v * v;
                    if (mv) {
                        const int wo = n & (Wo - 1);
                        const int r  = n >> lWo;
                        const int ho = r & (Ho - 1);
                        const int b_ = r >> lHo;
                        Y[((size_t)b_ * M + m) * HW + (ho << lWo) + wo] = v;
                    }
                }
#pragma unroll
                for (int mask = 1; mask < 16; mask <<= 1) {
                    s += __shfl_xor(s, mask);
                    q += __shfl_xor(q, mask);
                }
                if (mv && l16 == 0)
                    part[(size_t)m * nBlkN + nblk] = make_float2(s, q);
            }
        }
    } else {
        // split-K: accumulate into zero-initialized Y (native f32 atomic add)
#pragma unroll
        for (int i = 0; i < MW; i++) {
#pragma unroll
            for (int j = 0; j < 4; j++) {
                const int n = n0 + j * 16 + l16;
                const int wo = n & (Wo - 1);
                const int r  = n >> lWo;
                const int ho = r & (Ho - 1);
                const int b_ = r >> lHo;
#pragma unroll
                for (int rr = 0; rr < 4; rr++) {
                    const int m = m0 + wrow + i * 16 + quad * 4 + rr;
                    if (m < M)
                        unsafeAtomicAdd(
                            &Y[((size_t)b_ * M + m) * HW + (ho << lWo) + wo],
                            acc[i][j][rr]);
                }
            }
        }
    }
}

// ---------------------------------------------------------------------------
// BN stats for split-K layers: grid (Co, 8), float partials -> part[c*8+sp].
// ---------------------------------------------------------------------------
__global__ __launch_bounds__(256) void bn_stats8_kernel(
    const float* __restrict__ Y, float2* __restrict__ part,
    int Co, int HW, int B)
{
    int co = blockIdx.x;
    int sp = blockIdx.y;
    int tid = threadIdx.x;
    int Nt = B * HW;
    int len = Nt >> 3;                  // Nt multiple of 8 (HW >= 512)
    int start = sp * len, end = start + len;
    float s = 0.f, q = 0.f;
    for (int idx = start + tid; idx < end; idx += 256) {
        int b = idx / HW; int o = idx - b * HW;
        float v = Y[((size_t)b * Co + co) * HW + o];
        s += v; q += v * v;
    }
    __shared__ float sh_s[256], sh_q[256];
    sh_s[tid] = s; sh_q[tid] = q;
    __syncthreads();
    for (int off = 128; off > 0; off >>= 1) {
        if (tid < off) { sh_s[tid] += sh_s[tid + off]; sh_q[tid] += sh_q[tid + off]; }
        __syncthreads();
    }
    if (tid == 0)
        part[co * 8 + sp] = make_float2(sh_s[0], sh_q[0]);
}

// ---------------------------------------------------------------------------
// BN finalize: one block per channel; reduce nBlkN partial slots -> {sc, sf}.
// ---------------------------------------------------------------------------
__global__ __launch_bounds__(256) void bn_finalize_kernel(
    const float2* __restrict__ part, float2* __restrict__ scSf,
    const float* __restrict__ g, const float* __restrict__ bb,
    int nBlkN, int Nt)
{
    int c = blockIdx.x;
    int tid = threadIdx.x;
    double s = 0.0, q = 0.0;
    for (int k = tid; k < nBlkN; k += 256) {
        float2 p = part[(size_t)c * nBlkN + k];
        s += p.x; q += p.y;
    }
    __shared__ double sh_s[256], sh_q[256];
    sh_s[tid] = s; sh_q[tid] = q;
    __syncthreads();
    for (int off = 128; off > 0; off >>= 1) {
        if (tid < off) { sh_s[tid] += sh_s[tid + off]; sh_q[tid] += sh_q[tid + off]; }
        __syncthreads();
    }
    if (tid == 0) {
        double mean = sh_s[0] / Nt;
        double var = sh_q[0] / Nt - mean * mean;
        if (var < 0.0) var = 0.0;
        float sc = g[c] / sqrtf((float)var + 1e-5f);
        scSf[c] = make_float2(sc, bb[c] - (float)mean * sc);
    }
}

// Normalize + ReLU using finalized per-channel {sc, sf}.
__global__ __launch_bounds__(256) void bn_apply_kernel(
    float* __restrict__ Y, const float2* __restrict__ scSf,
    int Co, int HW, int total)
{
    int idx = blockIdx.x * 256 + threadIdx.x;
    if (idx >= total) return;
    int c = (idx / HW) % Co;
    float2 s = scSf[c];
    float v = Y[idx] * s.x + s.y;
    Y[idx] = v > 0.f ? v : 0.f;
}

// ---------------------------------------------------------------------------
// Host orchestration. Workspace ~36 MB: part 512KB + scSf 2KB + activations
// 29.4MB + Abf 5.1MB. Scratch Q reuse by lifetime: x1=Q (L1-2), x3=Q (L3-4),
// x4=Q (L5-6), x41=Q+512K (L6-7), x5=Q+1M (L7-8).
// ---------------------------------------------------------------------------
extern "C" void kernel_launch(void* const* d_in, const int* in_sizes, int n_in,
                              void* d_out, int out_size, void* d_ws, size_t ws_size,
                              hipStream_t stream)
{
    const int B = 4;
    char* ws = (char*)d_ws;
    size_t off = 0;
    auto allocb = [&](size_t bytes) -> void* {
        void* p = ws + off;
        off = (off + bytes + 255) & ~(size_t)255;
        return p;
    };

    float2* part = (float2*)allocb((size_t)65536 * sizeof(float2));
    float2* scSf = (float2*)allocb(256 * sizeof(float2));
    float* x2  = (float*)allocb((size_t)B * 64  * 64 * 128 * 4);
    float* x31 = (float*)allocb((size_t)B * 128 * 32 * 64 * 4);
    float* Q   = (float*)allocb((size_t)B * 32  * 128 * 256 * 4);
    float* x1  = Q;
    float* x3  = Q;
    float* x4  = Q;
    float* x41 = Q + (size_t)B * 256 * 16 * 32;
    float* x5  = Q + 2 * (size_t)B * 256 * 16 * 32;

    //                      1     2     3    31     4    41     5     6
    static const int kH[8]  = {256, 128,  64,  32,  32,  16,  32,  64};
    static const int kW[8]  = {512, 256, 128,  64,  64,  32,  64, 128};
    static const int kK[8]  = {  7,   5,   5,   3,   3,   3,   3,   3};
    static const int kSt[8] = {  2,   2,   2,   1,   2,   1,   1,   1};
    static const int kC[8]  = {  6,  32,  64, 128, 128, 256, 384, 320};
    static const int kM[8]  = { 32,  64, 128, 128, 256, 256, 256, 128};
    // Grid rule (r12-r14): every conv wants >=4 blocks/CU where SK permits.
    // r15: L6 2blk/CU -> SK=2 (1024 blocks); L5 SK=4 (1024 blocks).
    static const int kMW[8] = {  1,   1,   1,   1,   1,   1,   2,   2};
    static const int kSK[8] = {  1,   1,   2,   2,   4,   4,   4,   2};

    int Cp_[8], Kp_[8], Mpad_[8];
    short* Abf[8];
    for (int i = 0; i < 8; i++) {
        int K2 = kK[i] * kK[i];
        int Cp = (kC[i] < 8) ? 8 : kC[i];
        int Kp = (K2 * Cp + 31) & ~31;
        int Mpad = (kM[i] + 63) & ~63;
        Cp_[i] = Cp; Kp_[i] = Kp; Mpad_[i] = Mpad;
        Abf[i] = (short*)allocb((size_t)Mpad * Kp * sizeof(short));
    }
    (void)ws_size; (void)in_sizes; (void)n_in; (void)out_size;

    struct LCfg { const float *s1, *s2; int C1, up; float delta; int widx; float* Y; };
    const float* input = (const float*)d_in[0];
    LCfg L[8] = {
        { input, nullptr,   6, 0, PI_F / 32.f,  1, x1  },
        { x1,    nullptr,  32, 0, PI_F / 16.f,  5, x2  },
        { x2,    nullptr,  64, 0, PI_F / 4.f,   9, x3  },
        { x3,    nullptr, 128, 0, PI_F / 4.f,  13, x31 },
        { x31,   nullptr, 128, 0, PI_F / 2.f,  17, x4  },
        { x4,    nullptr, 256, 0, PI_F / 2.f,  21, x41 },
        { x41,   x31,     256, 1, PI_F / 4.f,  25, x5  },
        { x5,    x2,      256, 1, PI_F / 8.f,  29, (float*)d_out },
    };

    for (int i = 0; i < 8; i++) {
        const LCfg& c = L[i];
        int H = kH[i], W = kW[i], k = kK[i], st = kSt[i];
        int Ho = H / st, Wo = W / st;
        int K2 = k * k;
        int C  = kC[i], M = kM[i];
        int HW = Ho * Wo;
        int N  = B * HW;
        int lWo = __builtin_ctz(Wo), lHo = __builtin_ctz(Ho);
        const float* Wt   = (const float*)d_in[c.widx];
        const float* gam  = (const float*)d_in[c.widx + 2];
        const float* bet  = (const float*)d_in[c.widx + 3];
        int total = B * M * HW;

        int tn = Mpad_[i] * Kp_[i];
        wtrans_kernel<<<dim3((tn + 255) / 256), dim3(256), 0, stream>>>(
            Wt, Abf[i], M, Mpad_[i], K2, C, Cp_[i], Kp_[i], C * K2);

        int MWi = kMW[i], SKi = kSK[i];
        int nBlkM = Mpad_[i] / (64 * MWi);
        int nBlkN = N / BNT;
        int totalBlk = nBlkN * nBlkM * SKi;        // % 8 == 0 for all layers
        int lgM = __builtin_ctz(nBlkM);

        if (SKi > 1)
            zero_kernel<<<dim3((total + 255) / 256), dim3(256), 0, stream>>>(
                c.Y, total);

        #define CONV_ARGS Abf[i], c.s1, c.s2, part, nBlkN, \
            c.C1, C, Cp_[i], H, W, c.up, K2, k, st, lWo, lHo, c.delta, \
            c.Y, M, Kp_[i], N, lgM
        if      (MWi == 1 && SKi == 1)
            sconv_mfma_kernel<1,1><<<dim3(totalBlk), dim3(256), 0, stream>>>(CONV_ARGS);
        else if (MWi == 1 && SKi == 2)
            sconv_mfma_kernel<1,2><<<dim3(totalBlk), dim3(256), 0, stream>>>(CONV_ARGS);
        else if (MWi == 1 && SKi == 4)
            sconv_mfma_kernel<1,4><<<dim3(totalBlk), dim3(256), 0, stream>>>(CONV_ARGS);
        else if (MWi == 2 && SKi == 2)
            sconv_mfma_kernel<2,2><<<dim3(totalBlk), dim3(256), 0, stream>>>(CONV_ARGS);
        else
            sconv_mfma_kernel<2,4><<<dim3(totalBlk), dim3(256), 0, stream>>>(CONV_ARGS);
        #undef CONV_ARGS

        int slots;
        if (SKi > 1) {
            bn_stats8_kernel<<<dim3(M, 8), dim3(256), 0, stream>>>(
                c.Y, part, M, HW, B);
            slots = 8;
        } else {
            slots = nBlkN;
        }
        bn_finalize_kernel<<<dim3(M), dim3(256), 0, stream>>>(
            part, scSf, gam, bet, slots, N);
        bn_apply_kernel<<<dim3(total / 256), dim3(256), 0, stream>>>(
            c.Y, scSf, M, HW, total);
    }
}

// Round 16
// 867.470 us; speedup vs baseline: 2.9171x; 1.0086x over previous
//
#include <hip/hip_runtime.h>
#include <cstddef>
#include <cstdint>

#define PI_F 3.14159265358979323846f

typedef __attribute__((ext_vector_type(8))) short short8;   // 8 bf16 = 4 VGPRs
typedef __attribute__((ext_vector_type(4))) float floatx4;  // MFMA acc

__device__ __forceinline__ short f2bf(float f) {
    union { float f; unsigned u; } v; v.f = f;
    unsigned r = v.u + 0x7FFFu + ((v.u >> 16) & 1u);   // RNE
    return (short)(r >> 16);
}

// ---------------------------------------------------------------------------
// Weight transpose+convert: Abf[m][k'] = bf16(A[m][c*K2 + tap]), k' = tap*Cp+c
// Zero-pads m in [M,Mpad), c in [C,Cp), tap in [K2, Kp/Cp) — the K padding
// is what makes SK-slice-aligned Kp exact (padded tiles multiply A=0).
// ---------------------------------------------------------------------------
__global__ __launch_bounds__(256) void wtrans_kernel(
    const float* __restrict__ A, short* __restrict__ Abf,
    int M, int Mpad, int K2, int C, int Cp, int Kp, int Korig)
{
    int idx = blockIdx.x * 256 + threadIdx.x;
    if (idx >= Mpad * Kp) return;
    int m = idx / Kp;
    int k = idx - m * Kp;
    int tap = (unsigned)k / (unsigned)Cp;
    int c   = k - tap * Cp;
    float v = 0.f;
    if (m < M && tap < K2 && c < C) v = A[(size_t)m * Korig + c * K2 + tap];
    Abf[idx] = f2bf(v);
}

__global__ __launch_bounds__(256) void zero_kernel(float* __restrict__ p, int n)
{
    int i = blockIdx.x * 256 + threadIdx.x;
    if (i < n) p[i] = 0.f;
}

// ---------------------------------------------------------------------------
// Fused spherical-conv GEMM, bf16 MFMA, channel-innermost K.
// ROUND-16: grid re-tune only (the knob that won r13/r14/r15). r15 counters:
// L6 at 1024 blocks (4 blk/CU) still occ 37.5% / VALU 45% -> more TLP
// available. New tuning via Kp padded to 32*SK multiples:
//   L6 SK=4 (2048 blocks), L2 SK=2 (1024), L3 SK=4 (1024), L31 SK=4 (1024).
// Split-K accumulates into zero-initialized Y via fp32 unsafeAtomicAdd
// (r14/r15-proven benign: spread over MBs; kslice bits keep slices of an
// n-block on one XCD so gather L2 reuse holds).
// Conv bias dropped everywhere (BN mean-subtraction cancels it exactly).
// ---------------------------------------------------------------------------
#define BNT 64
#define BKT 32
#define LDK 40

template<int MW, int SK>
__global__ __launch_bounds__(256) void sconv_mfma_kernel(
    const short* __restrict__ Abf,
    const float* __restrict__ src1, const float* __restrict__ src2,
    float2* __restrict__ part, int nBlkN,
    int C1, int Ctot, int Cp, int H, int W, int up1,
    int K2, int ksz, int stride, int lWo, int lHo, float delta,
    float* __restrict__ Y, int M, int Kp, int N, int lgM)
{
    __shared__ short Bs[BNT][LDK];
    __shared__ float4 tab[64];          // max nHo*K2 = 49 over all layers

    constexpr int LGSK = (SK == 1) ? 0 : ((SK == 2) ? 1 : 2);

    const int tid = threadIdx.x;
    // ---- XCD swizzle (total % 8 == 0 for all layers) ----
    const int total = gridDim.x;
    const int pid = blockIdx.x;
    const int logical = (pid & 7) * (total >> 3) + (pid >> 3);
    const int mblk = logical & ((1 << lgM) - 1);
    const int rest = logical >> lgM;
    const int kslice = rest & (SK - 1);
    const int nblk = rest >> LGSK;
    const int m0 = mblk * (MW * 64);
    const int n0 = nblk * BNT;

    const int Wo  = 1 << lWo;
    const int Ho  = 1 << lHo;
    const int HW  = 1 << (lWo + lHo);

    // ---- per-block grid table: (hoLocal, tap) -> {fr, dcol, r0i, r1i} ----
    const int nHo  = (lWo >= 6) ? 1 : (BNT >> lWo);
    const int nEnt = nHo * K2;
    const int hoBase = (n0 >> lWo) & (Ho - 1);
    if (tid < nEnt) {
        int hoL = tid / K2;
        int i   = tid - hoL * K2;
        int ho_g = hoBase + hoL;
        int jy = i / ksz, jx = i - jy * ksz;
        float halfk = (ksz - 1) * 0.5f;
        float yy = tanf(delta / (float)ksz * ((float)jy - halfk));
        float xx = tanf(delta / (float)ksz * ((float)jx - halfk));
        float rho = sqrtf(xx * xx + yy * yy);
        float rho_s = (rho == 0.f) ? 1.f : rho;
        float nu = atanf(rho);
        float lat0 = PI_F * 0.5f - ((float)(ho_g * stride) + 0.5f) * (PI_F / (float)H);
        float sl = sinf(lat0), cl = cosf(lat0);
        float sn = sinf(nu),  cn = cosf(nu);
        float arg = cn * sl + (yy / rho_s) * sn * cl;
        arg = fminf(1.f, fmaxf(-1.f, arg));
        float lat = asinf(arg);
        float dlon = atan2f(xx * sn, rho * cl * cn - yy * sl * sn);
        float row = (PI_F * 0.5f - lat) / PI_F * (float)H - 0.5f;
        float dcol = dlon / (2.f * PI_F) * (float)W;
        float r0f = floorf(row);
        float fr = row - r0f;
        int r0 = (int)r0f;
        int r0i = min(max(r0, 0), H - 1);
        int r1i = min(max(r0 + 1, 0), H - 1);
        tab[tid] = make_float4(fr, dcol, __int_as_float(r0i), __int_as_float(r1i));
    }

    // ---- B staging geometry (lane nn = coalesced wo) ----
    const int nn    = tid & 63;
    const int kslot = tid >> 6;         // wave-uniform
    const int n_s  = n0 + nn;
    const int wo_s = n_s & (Wo - 1);
    const int hoL_s = nn >> lWo;
    const int b_s  = n_s >> (lWo + lHo);   // block-uniform (HW multiple of 64)
    const int tabBase = hoL_s * K2;
    const float wo_px = (float)(wo_s * stride);
    const int Hs = H >> up1, Ws = W >> up1;
    const int plane1 = Hs * Ws;
    const int plane2 = H * W;
    const unsigned boff1 = (unsigned)(b_s * C1 * plane1);
    const unsigned boff2 = (unsigned)(b_s * (Ctot - C1) * plane2);

    // ---- K-slice bounds + (tap, cb) init at slice start ----
    const int Tper = (Kp / BKT) / SK;
    const int t0 = kslice * Tper;
    const bool smallC = (Cp < 32);      // layer 1 only (Cp=8, never split)
    int tap, cb;
    if (smallC) { tap = kslot; cb = 0; }
    else {
        int prog = t0 * BKT;            // Cp % 32 == 0 for all split layers
        tap = prog / Cp;
        cb  = prog - tap * Cp + kslot * 8;
    }
    const int dtap = smallC ? (32 / Cp) : 0;

    // ---- wave/lane decomposition: wave tile = MW*16 rows x 64 cols ----
    const int wave = tid >> 6;
    const int wrow = wave * (MW * 16);
    const int lane = tid & 63;
    const int l16  = lane & 15;
    const int quad = lane >> 4;

    const short* pA[MW];
#pragma unroll
    for (int i = 0; i < MW; i++)
        pA[i] = Abf + (size_t)(m0 + wrow + i * 16 + l16) * Kp + quad * 8;

    floatx4 acc[MW][4];
#pragma unroll
    for (int i = 0; i < MW; i++)
#pragma unroll
        for (int j = 0; j < 4; j++)
            acc[i][j] = (floatx4){0.f, 0.f, 0.f, 0.f};

    __syncthreads();   // table ready

    for (int t = t0; t < t0 + Tper; t++) {
        const int k0 = t * BKT;
        // ---- B tile: one tap, 8 channels (inline gather) ----
        {
            const int tapc = min(tap, K2 - 1);       // clamp for K-pad region
            const float4 e = tab[tabBase + tapc];
            const float fr = e.x;
            const float col = wo_px + e.y;
            const int r0i = __float_as_int(e.z);
            const int r1i = __float_as_int(e.w);
            const float cf = floorf(col);
            const float fc = col - cf;
            const int c0 = ((int)cf) & (W - 1);
            const int c1 = (c0 + 1) & (W - 1);
            const float w00 = (1.f - fr) * (1.f - fc);
            const float w01 = (1.f - fr) * fc;
            const float w10 = fr * (1.f - fc);
            const float w11 = fr * fc;

            const float* src; unsigned i00, i01, i10, i11, plane;
            if (cb < C1) {               // wave-uniform branch
                const int ra = (r0i >> up1) * Ws, rb = (r1i >> up1) * Ws;
                const int ca = c0 >> up1, cx = c1 >> up1;
                const unsigned base = boff1 + (unsigned)cb * plane1;
                i00 = base + ra + ca; i01 = base + ra + cx;
                i10 = base + rb + ca; i11 = base + rb + cx;
                plane = plane1; src = src1;
            } else {
                const int ra = r0i * W, rb = r1i * W;
                const unsigned base = boff2 + (unsigned)(cb - C1) * plane2;
                i00 = base + ra + c0; i01 = base + ra + c1;
                i10 = base + rb + c0; i11 = base + rb + c1;
                plane = plane2; src = src2;
            }
            short t8[8];
#pragma unroll
            for (int j = 0; j < 8; j++) {
                float v = 0.f;
                if (cb + j < Ctot) {     // guard BEFORE loads (L1: src2 null)
                    v = w00 * src[i00] + w01 * src[i01]
                      + w10 * src[i10] + w11 * src[i11];
                }
                t8[j] = f2bf(v);
                i00 += plane; i01 += plane; i10 += plane; i11 += plane;
            }
            *(short8*)&Bs[nn][kslot * 8] = *(short8*)&t8[0];
        }
        __syncthreads();

        short8 af[MW];
#pragma unroll
        for (int i = 0; i < MW; i++)
            af[i] = *(const short8*)(pA[i] + k0);
        short8 bf[4];
#pragma unroll
        for (int j = 0; j < 4; j++)
            bf[j] = *(const short8*)&Bs[j * 16 + l16][quad * 8];
#pragma unroll
        for (int i = 0; i < MW; i++)
#pragma unroll
            for (int j = 0; j < 4; j++)
                acc[i][j] = __builtin_amdgcn_mfma_f32_16x16x32_bf16(
                    af[i], bf[j], acc[i][j], 0, 0, 0);
        __syncthreads();

        // advance (tap, cb)
        if (smallC) { tap += dtap; }
        else { cb += 32; if (cb >= Cp) { cb -= Cp; tap++; } }
    }

    // ---- epilogue (C/D layout col=lane&15, row=quad*4+reg) ----
    if (SK == 1) {
        // plain store + BN partials to UNIQUE per-(m,nblk) slots (no atomics)
#pragma unroll
        for (int i = 0; i < MW; i++) {
#pragma unroll
            for (int rr = 0; rr < 4; rr++) {
                const int m = m0 + wrow + i * 16 + quad * 4 + rr;
                const bool mv = (m < M);
                float s = 0.f, q = 0.f;
#pragma unroll
                for (int j = 0; j < 4; j++) {
                    const int n = n0 + j * 16 + l16;
                    const float v = acc[i][j][rr];
                    s += v; q += v * v;
                    if (mv) {
                        const int wo = n & (Wo - 1);
                        const int r  = n >> lWo;
                        const int ho = r & (Ho - 1);
                        const int b_ = r >> lHo;
                        Y[((size_t)b_ * M + m) * HW + (ho << lWo) + wo] = v;
                    }
                }
#pragma unroll
                for (int mask = 1; mask < 16; mask <<= 1) {
                    s += __shfl_xor(s, mask);
                    q += __shfl_xor(q, mask);
                }
                if (mv && l16 == 0)
                    part[(size_t)m * nBlkN + nblk] = make_float2(s, q);
            }
        }
    } else {
        // split-K: accumulate into zero-initialized Y (native f32 atomic add)
#pragma unroll
        for (int i = 0; i < MW; i++) {
#pragma unroll
            for (int j = 0; j < 4; j++) {
                const int n = n0 + j * 16 + l16;
                const int wo = n & (Wo - 1);
                const int r  = n >> lWo;
                const int ho = r & (Ho - 1);
                const int b_ = r >> lHo;
#pragma unroll
                for (int rr = 0; rr < 4; rr++) {
                    const int m = m0 + wrow + i * 16 + quad * 4 + rr;
                    if (m < M)
                        unsafeAtomicAdd(
                            &Y[((size_t)b_ * M + m) * HW + (ho << lWo) + wo],
                            acc[i][j][rr]);
                }
            }
        }
    }
}

// ---------------------------------------------------------------------------
// BN stats for split-K layers: grid (Co, 8), float partials -> part[c*8+sp].
// ---------------------------------------------------------------------------
__global__ __launch_bounds__(256) void bn_stats8_kernel(
    const float* __restrict__ Y, float2* __restrict__ part,
    int Co, int HW, int B)
{
    int co = blockIdx.x;
    int sp = blockIdx.y;
    int tid = threadIdx.x;
    int Nt = B * HW;
    int len = Nt >> 3;                  // Nt multiple of 8 (HW >= 512)
    int start = sp * len, end = start + len;
    float s = 0.f, q = 0.f;
    for (int idx = start + tid; idx < end; idx += 256) {
        int b = idx / HW; int o = idx - b * HW;
        float v = Y[((size_t)b * Co + co) * HW + o];
        s += v; q += v * v;
    }
    __shared__ float sh_s[256], sh_q[256];
    sh_s[tid] = s; sh_q[tid] = q;
    __syncthreads();
    for (int off = 128; off > 0; off >>= 1) {
        if (tid < off) { sh_s[tid] += sh_s[tid + off]; sh_q[tid] += sh_q[tid + off]; }
        __syncthreads();
    }
    if (tid == 0)
        part[co * 8 + sp] = make_float2(sh_s[0], sh_q[0]);
}

// ---------------------------------------------------------------------------
// BN finalize: one block per channel; reduce nBlkN partial slots -> {sc, sf}.
// ---------------------------------------------------------------------------
__global__ __launch_bounds__(256) void bn_finalize_kernel(
    const float2* __restrict__ part, float2* __restrict__ scSf,
    const float* __restrict__ g, const float* __restrict__ bb,
    int nBlkN, int Nt)
{
    int c = blockIdx.x;
    int tid = threadIdx.x;
    double s = 0.0, q = 0.0;
    for (int k = tid; k < nBlkN; k += 256) {
        float2 p = part[(size_t)c * nBlkN + k];
        s += p.x; q += p.y;
    }
    __shared__ double sh_s[256], sh_q[256];
    sh_s[tid] = s; sh_q[tid] = q;
    __syncthreads();
    for (int off = 128; off > 0; off >>= 1) {
        if (tid < off) { sh_s[tid] += sh_s[tid + off]; sh_q[tid] += sh_q[tid + off]; }
        __syncthreads();
    }
    if (tid == 0) {
        double mean = sh_s[0] / Nt;
        double var = sh_q[0] / Nt - mean * mean;
        if (var < 0.0) var = 0.0;
        float sc = g[c] / sqrtf((float)var + 1e-5f);
        scSf[c] = make_float2(sc, bb[c] - (float)mean * sc);
    }
}

// Normalize + ReLU using finalized per-channel {sc, sf}.
__global__ __launch_bounds__(256) void bn_apply_kernel(
    float* __restrict__ Y, const float2* __restrict__ scSf,
    int Co, int HW, int total)
{
    int idx = blockIdx.x * 256 + threadIdx.x;
    if (idx >= total) return;
    int c = (idx / HW) % Co;
    float2 s = scSf[c];
    float v = Y[idx] * s.x + s.y;
    Y[idx] = v > 0.f ? v : 0.f;
}

// ---------------------------------------------------------------------------
// Host orchestration. Workspace ~36 MB: part 512KB + scSf 2KB + activations
// 29.4MB + Abf 5.3MB. Scratch Q reuse by lifetime: x1=Q (L1-2), x3=Q (L3-4),
// x4=Q (L5-6), x41=Q+512K (L6-7), x5=Q+1M (L7-8).
// ---------------------------------------------------------------------------
extern "C" void kernel_launch(void* const* d_in, const int* in_sizes, int n_in,
                              void* d_out, int out_size, void* d_ws, size_t ws_size,
                              hipStream_t stream)
{
    const int B = 4;
    char* ws = (char*)d_ws;
    size_t off = 0;
    auto allocb = [&](size_t bytes) -> void* {
        void* p = ws + off;
        off = (off + bytes + 255) & ~(size_t)255;
        return p;
    };

    float2* part = (float2*)allocb((size_t)65536 * sizeof(float2));
    float2* scSf = (float2*)allocb(256 * sizeof(float2));
    float* x2  = (float*)allocb((size_t)B * 64  * 64 * 128 * 4);
    float* x31 = (float*)allocb((size_t)B * 128 * 32 * 64 * 4);
    float* Q   = (float*)allocb((size_t)B * 32  * 128 * 256 * 4);
    float* x1  = Q;
    float* x3  = Q;
    float* x4  = Q;
    float* x41 = Q + (size_t)B * 256 * 16 * 32;
    float* x5  = Q + 2 * (size_t)B * 256 * 16 * 32;

    //                      1     2     3    31     4    41     5     6
    static const int kH[8]  = {256, 128,  64,  32,  32,  16,  32,  64};
    static const int kW[8]  = {512, 256, 128,  64,  64,  32,  64, 128};
    static const int kK[8]  = {  7,   5,   5,   3,   3,   3,   3,   3};
    static const int kSt[8] = {  2,   2,   2,   1,   2,   1,   1,   1};
    static const int kC[8]  = {  6,  32,  64, 128, 128, 256, 384, 320};
    static const int kM[8]  = { 32,  64, 128, 128, 256, 256, 256, 128};
    // Grid rule (r12-r15): maximize blocks/CU. r16: L2 SK=2 (1024 blocks),
    // L3 SK=4 (1024), L31 SK=4 (1024), L6 SK=4 (2048). Kp padded to 32*SK.
    static const int kMW[8] = {  1,   1,   1,   1,   1,   1,   2,   2};
    static const int kSK[8] = {  1,   2,   4,   4,   4,   4,   4,   4};

    int Cp_[8], Kp_[8], Mpad_[8];
    short* Abf[8];
    for (int i = 0; i < 8; i++) {
        int K2 = kK[i] * kK[i];
        int Cp = (kC[i] < 8) ? 8 : kC[i];
        int gran = 32 * kSK[i];
        int Kp = (K2 * Cp + gran - 1) / gran * gran;   // SK-slice aligned
        int Mpad = (kM[i] + 63) & ~63;
        Cp_[i] = Cp; Kp_[i] = Kp; Mpad_[i] = Mpad;
        Abf[i] = (short*)allocb((size_t)Mpad * Kp * sizeof(short));
    }
    (void)ws_size; (void)in_sizes; (void)n_in; (void)out_size;

    struct LCfg { const float *s1, *s2; int C1, up; float delta; int widx; float* Y; };
    const float* input = (const float*)d_in[0];
    LCfg L[8] = {
        { input, nullptr,   6, 0, PI_F / 32.f,  1, x1  },
        { x1,    nullptr,  32, 0, PI_F / 16.f,  5, x2  },
        { x2,    nullptr,  64, 0, PI_F / 4.f,   9, x3  },
        { x3,    nullptr, 128, 0, PI_F / 4.f,  13, x31 },
        { x31,   nullptr, 128, 0, PI_F / 2.f,  17, x4  },
        { x4,    nullptr, 256, 0, PI_F / 2.f,  21, x41 },
        { x41,   x31,     256, 1, PI_F / 4.f,  25, x5  },
        { x5,    x2,      256, 1, PI_F / 8.f,  29, (float*)d_out },
    };

    for (int i = 0; i < 8; i++) {
        const LCfg& c = L[i];
        int H = kH[i], W = kW[i], k = kK[i], st = kSt[i];
        int Ho = H / st, Wo = W / st;
        int K2 = k * k;
        int C  = kC[i], M = kM[i];
        int HW = Ho * Wo;
        int N  = B * HW;
        int lWo = __builtin_ctz(Wo), lHo = __builtin_ctz(Ho);
        const float* Wt   = (const float*)d_in[c.widx];
        const float* gam  = (const float*)d_in[c.widx + 2];
        const float* bet  = (const float*)d_in[c.widx + 3];
        int total = B * M * HW;

        int tn = Mpad_[i] * Kp_[i];
        wtrans_kernel<<<dim3((tn + 255) / 256), dim3(256), 0, stream>>>(
            Wt, Abf[i], M, Mpad_[i], K2, C, Cp_[i], Kp_[i], C * K2);

        int MWi = kMW[i], SKi = kSK[i];
        int nBlkM = Mpad_[i] / (64 * MWi);
        int nBlkN = N / BNT;
        int totalBlk = nBlkN * nBlkM * SKi;        // % 8 == 0 for all layers
        int lgM = __builtin_ctz(nBlkM);

        if (SKi > 1)
            zero_kernel<<<dim3((total + 255) / 256), dim3(256), 0, stream>>>(
                c.Y, total);

        #define CONV_ARGS Abf[i], c.s1, c.s2, part, nBlkN, \
            c.C1, C, Cp_[i], H, W, c.up, K2, k, st, lWo, lHo, c.delta, \
            c.Y, M, Kp_[i], N, lgM
        if      (MWi == 1 && SKi == 1)
            sconv_mfma_kernel<1,1><<<dim3(totalBlk), dim3(256), 0, stream>>>(CONV_ARGS);
        else if (MWi == 1 && SKi == 2)
            sconv_mfma_kernel<1,2><<<dim3(totalBlk), dim3(256), 0, stream>>>(CONV_ARGS);
        else if (MWi == 1 && SKi == 4)
            sconv_mfma_kernel<1,4><<<dim3(totalBlk), dim3(256), 0, stream>>>(CONV_ARGS);
        else if (MWi == 2 && SKi == 2)
            sconv_mfma_kernel<2,2><<<dim3(totalBlk), dim3(256), 0, stream>>>(CONV_ARGS);
        else
            sconv_mfma_kernel<2,4><<<dim3(totalBlk), dim3(256), 0, stream>>>(CONV_ARGS);
        #undef CONV_ARGS

        int slots;
        if (SKi > 1) {
            bn_stats8_kernel<<<dim3(M, 8), dim3(256), 0, stream>>>(
                c.Y, part, M, HW, B);
            slots = 8;
        } else {
            slots = nBlkN;
        }
        bn_finalize_kernel<<<dim3(M), dim3(256), 0, stream>>>(
            part, scSf, gam, bet, slots, N);
        bn_apply_kernel<<<dim3(total / 256), dim3(256), 0, stream>>>(
            c.Y, scSf, M, HW, total);
    }
}

// Round 17
// 850.217 us; speedup vs baseline: 2.9763x; 1.0203x over previous
//
#include <hip/hip_runtime.h>
#include <cstddef>
#include <cstdint>

#define PI_F 3.14159265358979323846f

typedef __attribute__((ext_vector_type(8))) short short8;   // 8 bf16 = 4 VGPRs
typedef __attribute__((ext_vector_type(4))) float floatx4;  // MFMA acc

__device__ __forceinline__ short f2bf(float f) {
    union { float f; unsigned u; } v; v.f = f;
    unsigned r = v.u + 0x7FFFu + ((v.u >> 16) & 1u);   // RNE
    return (short)(r >> 16);
}

// ---------------------------------------------------------------------------
// Weight transpose+convert: Abf[m][k'] = bf16(A[m][c*K2 + tap]), k' = tap*Cp+c
// Zero-pads m in [M,Mpad), c in [C,Cp), tap in [K2, Kp/Cp).
// ---------------------------------------------------------------------------
__global__ __launch_bounds__(256) void wtrans_kernel(
    const float* __restrict__ A, short* __restrict__ Abf,
    int M, int Mpad, int K2, int C, int Cp, int Kp, int Korig)
{
    int idx = blockIdx.x * 256 + threadIdx.x;
    if (idx >= Mpad * Kp) return;
    int m = idx / Kp;
    int k = idx - m * Kp;
    int tap = (unsigned)k / (unsigned)Cp;
    int c   = k - tap * Cp;
    float v = 0.f;
    if (m < M && tap < K2 && c < C) v = A[(size_t)m * Korig + c * K2 + tap];
    Abf[idx] = f2bf(v);
}

__global__ __launch_bounds__(256) void zero_kernel(float* __restrict__ p, int n)
{
    int i = blockIdx.x * 256 + threadIdx.x;
    if (i < n) p[i] = 0.f;
}

// Fused zero of the three non-aliased SK outputs (x2, x31, d_out) — hoisted
// to the start of the call (nothing touches them before their conv).
__global__ __launch_bounds__(256) void zero3_kernel(
    float* __restrict__ a, int na, float* __restrict__ b, int nb,
    float* __restrict__ c, int nc)
{
    int i = blockIdx.x * 256 + threadIdx.x;
    if (i < na) { a[i] = 0.f; return; }
    i -= na;
    if (i < nb) { b[i] = 0.f; return; }
    i -= nb;
    if (i < nc) c[i] = 0.f;
}

// ---------------------------------------------------------------------------
// Fused spherical-conv GEMM, bf16 MFMA, channel-innermost K.
// ROUND-17: DOUBLE-BUFFERED B-tile LDS -> ONE barrier per K-tile (write
// Bs[t&1] -> barrier -> MFMA reads Bs[t&1]; trailing barrier provably
// unnecessary with two buffers: iter t+2's write to buf(t&1) is ordered
// after barrier(t+1), which any wave reaches only after its MFMA(t) reads).
// r16 counters: VALU 48% / occ 43% -> residual stall was correlated
// 2-barrier waiting, not issue or memory bandwidth.
// L6 back to SK=2 (r16: SK=4 = 161us vs SK=2 = 158us, 2x atomic WRITE).
// XCD swizzle + split-K atomics + epilogue BN partials per r11-r16.
// ---------------------------------------------------------------------------
#define BNT 64
#define BKT 32
#define LDK 40

template<int MW, int SK>
__global__ __launch_bounds__(256) void sconv_mfma_kernel(
    const short* __restrict__ Abf,
    const float* __restrict__ src1, const float* __restrict__ src2,
    float2* __restrict__ part, int nBlkN,
    int C1, int Ctot, int Cp, int H, int W, int up1,
    int K2, int ksz, int stride, int lWo, int lHo, float delta,
    float* __restrict__ Y, int M, int Kp, int N, int lgM)
{
    __shared__ short Bs[2][BNT][LDK];   // double buffer: one barrier/tile
    __shared__ float4 tab[64];          // max nHo*K2 = 49 over all layers

    constexpr int LGSK = (SK == 1) ? 0 : ((SK == 2) ? 1 : 2);

    const int tid = threadIdx.x;
    // ---- XCD swizzle (total % 8 == 0 for all layers) ----
    const int total = gridDim.x;
    const int pid = blockIdx.x;
    const int logical = (pid & 7) * (total >> 3) + (pid >> 3);
    const int mblk = logical & ((1 << lgM) - 1);
    const int rest = logical >> lgM;
    const int kslice = rest & (SK - 1);
    const int nblk = rest >> LGSK;
    const int m0 = mblk * (MW * 64);
    const int n0 = nblk * BNT;

    const int Wo  = 1 << lWo;
    const int Ho  = 1 << lHo;
    const int HW  = 1 << (lWo + lHo);

    // ---- per-block grid table: (hoLocal, tap) -> {fr, dcol, r0i, r1i} ----
    const int nHo  = (lWo >= 6) ? 1 : (BNT >> lWo);
    const int nEnt = nHo * K2;
    const int hoBase = (n0 >> lWo) & (Ho - 1);
    if (tid < nEnt) {
        int hoL = tid / K2;
        int i   = tid - hoL * K2;
        int ho_g = hoBase + hoL;
        int jy = i / ksz, jx = i - jy * ksz;
        float halfk = (ksz - 1) * 0.5f;
        float yy = tanf(delta / (float)ksz * ((float)jy - halfk));
        float xx = tanf(delta / (float)ksz * ((float)jx - halfk));
        float rho = sqrtf(xx * xx + yy * yy);
        float rho_s = (rho == 0.f) ? 1.f : rho;
        float nu = atanf(rho);
        float lat0 = PI_F * 0.5f - ((float)(ho_g * stride) + 0.5f) * (PI_F / (float)H);
        float sl = sinf(lat0), cl = cosf(lat0);
        float sn = sinf(nu),  cn = cosf(nu);
        float arg = cn * sl + (yy / rho_s) * sn * cl;
        arg = fminf(1.f, fmaxf(-1.f, arg));
        float lat = asinf(arg);
        float dlon = atan2f(xx * sn, rho * cl * cn - yy * sl * sn);
        float row = (PI_F * 0.5f - lat) / PI_F * (float)H - 0.5f;
        float dcol = dlon / (2.f * PI_F) * (float)W;
        float r0f = floorf(row);
        float fr = row - r0f;
        int r0 = (int)r0f;
        int r0i = min(max(r0, 0), H - 1);
        int r1i = min(max(r0 + 1, 0), H - 1);
        tab[tid] = make_float4(fr, dcol, __int_as_float(r0i), __int_as_float(r1i));
    }

    // ---- B staging geometry (lane nn = coalesced wo) ----
    const int nn    = tid & 63;
    const int kslot = tid >> 6;         // wave-uniform
    const int n_s  = n0 + nn;
    const int wo_s = n_s & (Wo - 1);
    const int hoL_s = nn >> lWo;
    const int b_s  = n_s >> (lWo + lHo);   // block-uniform (HW multiple of 64)
    const int tabBase = hoL_s * K2;
    const float wo_px = (float)(wo_s * stride);
    const int Hs = H >> up1, Ws = W >> up1;
    const int plane1 = Hs * Ws;
    const int plane2 = H * W;
    const unsigned boff1 = (unsigned)(b_s * C1 * plane1);
    const unsigned boff2 = (unsigned)(b_s * (Ctot - C1) * plane2);

    // ---- K-slice bounds + (tap, cb) init at slice start ----
    const int Tper = (Kp / BKT) / SK;
    const int t0 = kslice * Tper;
    const bool smallC = (Cp < 32);      // layer 1 only (Cp=8, never split)
    int tap, cb;
    if (smallC) { tap = kslot; cb = 0; }
    else {
        int prog = t0 * BKT;            // Cp % 32 == 0 for all split layers
        tap = prog / Cp;
        cb  = prog - tap * Cp + kslot * 8;
    }
    const int dtap = smallC ? (32 / Cp) : 0;

    // ---- wave/lane decomposition: wave tile = MW*16 rows x 64 cols ----
    const int wave = tid >> 6;
    const int wrow = wave * (MW * 16);
    const int lane = tid & 63;
    const int l16  = lane & 15;
    const int quad = lane >> 4;

    const short* pA[MW];
#pragma unroll
    for (int i = 0; i < MW; i++)
        pA[i] = Abf + (size_t)(m0 + wrow + i * 16 + l16) * Kp + quad * 8;

    floatx4 acc[MW][4];
#pragma unroll
    for (int i = 0; i < MW; i++)
#pragma unroll
        for (int j = 0; j < 4; j++)
            acc[i][j] = (floatx4){0.f, 0.f, 0.f, 0.f};

    __syncthreads();   // table ready

    for (int t = t0; t < t0 + Tper; t++) {
        const int k0 = t * BKT;
        const int buf = t & 1;
        // ---- B tile: one tap, 8 channels (inline gather) ----
        {
            const int tapc = min(tap, K2 - 1);       // clamp for K-pad region
            const float4 e = tab[tabBase + tapc];
            const float fr = e.x;
            const float col = wo_px + e.y;
            const int r0i = __float_as_int(e.z);
            const int r1i = __float_as_int(e.w);
            const float cf = floorf(col);
            const float fc = col - cf;
            const int c0 = ((int)cf) & (W - 1);
            const int c1 = (c0 + 1) & (W - 1);
            const float w00 = (1.f - fr) * (1.f - fc);
            const float w01 = (1.f - fr) * fc;
            const float w10 = fr * (1.f - fc);
            const float w11 = fr * fc;

            const float* src; unsigned i00, i01, i10, i11, plane;
            if (cb < C1) {               // wave-uniform branch
                const int ra = (r0i >> up1) * Ws, rb = (r1i >> up1) * Ws;
                const int ca = c0 >> up1, cx = c1 >> up1;
                const unsigned base = boff1 + (unsigned)cb * plane1;
                i00 = base + ra + ca; i01 = base + ra + cx;
                i10 = base + rb + ca; i11 = base + rb + cx;
                plane = plane1; src = src1;
            } else {
                const int ra = r0i * W, rb = r1i * W;
                const unsigned base = boff2 + (unsigned)(cb - C1) * plane2;
                i00 = base + ra + c0; i01 = base + ra + c1;
                i10 = base + rb + c0; i11 = base + rb + c1;
                plane = plane2; src = src2;
            }
            short t8[8];
#pragma unroll
            for (int j = 0; j < 8; j++) {
                float v = 0.f;
                if (cb + j < Ctot) {     // guard BEFORE loads (L1: src2 null)
                    v = w00 * src[i00] + w01 * src[i01]
                      + w10 * src[i10] + w11 * src[i11];
                }
                t8[j] = f2bf(v);
                i00 += plane; i01 += plane; i10 += plane; i11 += plane;
            }
            *(short8*)&Bs[buf][nn][kslot * 8] = *(short8*)&t8[0];
        }
        __syncthreads();                 // the ONLY barrier per tile

        short8 af[MW];
#pragma unroll
        for (int i = 0; i < MW; i++)
            af[i] = *(const short8*)(pA[i] + k0);
        short8 bf[4];
#pragma unroll
        for (int j = 0; j < 4; j++)
            bf[j] = *(const short8*)&Bs[buf][j * 16 + l16][quad * 8];
#pragma unroll
        for (int i = 0; i < MW; i++)
#pragma unroll
            for (int j = 0; j < 4; j++)
                acc[i][j] = __builtin_amdgcn_mfma_f32_16x16x32_bf16(
                    af[i], bf[j], acc[i][j], 0, 0, 0);

        // advance (tap, cb); next iteration writes the OTHER buffer
        if (smallC) { tap += dtap; }
        else { cb += 32; if (cb >= Cp) { cb -= Cp; tap++; } }
    }

    // ---- epilogue (C/D layout col=lane&15, row=quad*4+reg) ----
    if (SK == 1) {
        // plain store + BN partials to UNIQUE per-(m,nblk) slots (no atomics)
#pragma unroll
        for (int i = 0; i < MW; i++) {
#pragma unroll
            for (int rr = 0; rr < 4; rr++) {
                const int m = m0 + wrow + i * 16 + quad * 4 + rr;
                const bool mv = (m < M);
                float s = 0.f, q = 0.f;
#pragma unroll
                for (int j = 0; j < 4; j++) {
                    const int n = n0 + j * 16 + l16;
                    const float v = acc[i][j][rr];
                    s += v; q += v * v;
                    if (mv) {
                        const int wo = n & (Wo - 1);
                        const int r  = n >> lWo;
                        const int ho = r & (Ho - 1);
                        const int b_ = r >> lHo;
                        Y[((size_t)b_ * M + m) * HW + (ho << lWo) + wo] = v;
                    }
                }
#pragma unroll
                for (int mask = 1; mask < 16; mask <<= 1) {
                    s += __shfl_xor(s, mask);
                    q += __shfl_xor(q, mask);
                }
                if (mv && l16 == 0)
                    part[(size_t)m * nBlkN + nblk] = make_float2(s, q);
            }
        }
    } else {
        // split-K: accumulate into zero-initialized Y (native f32 atomic add)
#pragma unroll
        for (int i = 0; i < MW; i++) {
#pragma unroll
            for (int j = 0; j < 4; j++) {
                const int n = n0 + j * 16 + l16;
                const int wo = n & (Wo - 1);
                const int r  = n >> lWo;
                const int ho = r & (Ho - 1);
                const int b_ = r >> lHo;
#pragma unroll
                for (int rr = 0; rr < 4; rr++) {
                    const int m = m0 + wrow + i * 16 + quad * 4 + rr;
                    if (m < M)
                        unsafeAtomicAdd(
                            &Y[((size_t)b_ * M + m) * HW + (ho << lWo) + wo],
                            acc[i][j][rr]);
                }
            }
        }
    }
}

// ---------------------------------------------------------------------------
// BN stats for split-K layers: grid (Co, 8), float partials -> part[c*8+sp].
// ---------------------------------------------------------------------------
__global__ __launch_bounds__(256) void bn_stats8_kernel(
    const float* __restrict__ Y, float2* __restrict__ part,
    int Co, int HW, int B)
{
    int co = blockIdx.x;
    int sp = blockIdx.y;
    int tid = threadIdx.x;
    int Nt = B * HW;
    int len = Nt >> 3;                  // Nt multiple of 8 (HW >= 512)
    int start = sp * len, end = start + len;
    float s = 0.f, q = 0.f;
    for (int idx = start + tid; idx < end; idx += 256) {
        int b = idx / HW; int o = idx - b * HW;
        float v = Y[((size_t)b * Co + co) * HW + o];
        s += v; q += v * v;
    }
    __shared__ float sh_s[256], sh_q[256];
    sh_s[tid] = s; sh_q[tid] = q;
    __syncthreads();
    for (int off = 128; off > 0; off >>= 1) {
        if (tid < off) { sh_s[tid] += sh_s[tid + off]; sh_q[tid] += sh_q[tid + off]; }
        __syncthreads();
    }
    if (tid == 0)
        part[co * 8 + sp] = make_float2(sh_s[0], sh_q[0]);
}

// ---------------------------------------------------------------------------
// BN finalize (L1 only, slots=nBlkN): reduce -> {sc, sf}.
// ---------------------------------------------------------------------------
__global__ __launch_bounds__(256) void bn_finalize_kernel(
    const float2* __restrict__ part, float2* __restrict__ scSf,
    const float* __restrict__ g, const float* __restrict__ bb,
    int nBlkN, int Nt)
{
    int c = blockIdx.x;
    int tid = threadIdx.x;
    double s = 0.0, q = 0.0;
    for (int k = tid; k < nBlkN; k += 256) {
        float2 p = part[(size_t)c * nBlkN + k];
        s += p.x; q += p.y;
    }
    __shared__ double sh_s[256], sh_q[256];
    sh_s[tid] = s; sh_q[tid] = q;
    __syncthreads();
    for (int off = 128; off > 0; off >>= 1) {
        if (tid < off) { sh_s[tid] += sh_s[tid + off]; sh_q[tid] += sh_q[tid + off]; }
        __syncthreads();
    }
    if (tid == 0) {
        double mean = sh_s[0] / Nt;
        double var = sh_q[0] / Nt - mean * mean;
        if (var < 0.0) var = 0.0;
        float sc = g[c] / sqrtf((float)var + 1e-5f);
        scSf[c] = make_float2(sc, bb[c] - (float)mean * sc);
    }
}

// Normalize + ReLU reading finalized {sc, sf} (L1 path).
__global__ __launch_bounds__(256) void bn_apply_kernel(
    float* __restrict__ Y, const float2* __restrict__ scSf,
    int Co, int HW, int total)
{
    int idx = blockIdx.x * 256 + threadIdx.x;
    if (idx >= total) return;
    int c = (idx / HW) % Co;
    float2 s = scSf[c];
    float v = Y[idx] * s.x + s.y;
    Y[idx] = v > 0.f ? v : 0.f;
}

// SK layers: finalize folded in — per-block reduce of the 8 partial slots
// (channel uniform per block since 256 | HW for all SK layers).
__global__ __launch_bounds__(256) void bn_apply_sk_kernel(
    float* __restrict__ Y, const float2* __restrict__ part,
    const float* __restrict__ g, const float* __restrict__ bb,
    int Co, int HW, int Nt, int total)
{
    int idx = blockIdx.x * 256 + threadIdx.x;
    int c = (idx / HW) % Co;
    __shared__ float s_sc, s_sf;
    if (threadIdx.x == 0) {
        double s = 0.0, q = 0.0;
        for (int p = 0; p < 8; p++) {
            float2 pp = part[c * 8 + p];
            s += pp.x; q += pp.y;
        }
        double mean = s / Nt;
        double var = q / Nt - mean * mean;
        if (var < 0.0) var = 0.0;
        float sc = g[c] / sqrtf((float)var + 1e-5f);
        s_sc = sc;
        s_sf = bb[c] - (float)mean * sc;
    }
    __syncthreads();
    if (idx >= total) return;
    float v = Y[idx] * s_sc + s_sf;
    Y[idx] = v > 0.f ? v : 0.f;
}

// ---------------------------------------------------------------------------
// Host orchestration. Workspace ~36 MB. Scratch Q reuse by lifetime:
// x1=Q (L1-2), x3=Q (L3-4), x4=Q (L5-6), x41=Q+512K (L6-7), x5=Q+1M (L7-8).
// Zeros for non-aliased SK outputs (x2, x31, d_out) hoisted+fused upfront;
// Q-aliased outputs (x3, x4, x41, x5) zeroed inline.
// ---------------------------------------------------------------------------
extern "C" void kernel_launch(void* const* d_in, const int* in_sizes, int n_in,
                              void* d_out, int out_size, void* d_ws, size_t ws_size,
                              hipStream_t stream)
{
    const int B = 4;
    char* ws = (char*)d_ws;
    size_t off = 0;
    auto allocb = [&](size_t bytes) -> void* {
        void* p = ws + off;
        off = (off + bytes + 255) & ~(size_t)255;
        return p;
    };

    float2* part = (float2*)allocb((size_t)65536 * sizeof(float2));
    float2* scSf = (float2*)allocb(256 * sizeof(float2));
    float* x2  = (float*)allocb((size_t)B * 64  * 64 * 128 * 4);
    float* x31 = (float*)allocb((size_t)B * 128 * 32 * 64 * 4);
    float* Q   = (float*)allocb((size_t)B * 32  * 128 * 256 * 4);
    float* x1  = Q;
    float* x3  = Q;
    float* x4  = Q;
    float* x41 = Q + (size_t)B * 256 * 16 * 32;
    float* x5  = Q + 2 * (size_t)B * 256 * 16 * 32;

    //                      1     2     3    31     4    41     5     6
    static const int kH[8]  = {256, 128,  64,  32,  32,  16,  32,  64};
    static const int kW[8]  = {512, 256, 128,  64,  64,  32,  64, 128};
    static const int kK[8]  = {  7,   5,   5,   3,   3,   3,   3,   3};
    static const int kSt[8] = {  2,   2,   2,   1,   2,   1,   1,   1};
    static const int kC[8]  = {  6,  32,  64, 128, 128, 256, 384, 320};
    static const int kM[8]  = { 32,  64, 128, 128, 256, 256, 256, 128};
    // Grid tuning (r12-r16): L6 SK=2 (r16: SK=4 neutral, 2x atomic WRITE).
    static const int kMW[8] = {  1,   1,   1,   1,   1,   1,   2,   2};
    static const int kSK[8] = {  1,   2,   4,   4,   4,   4,   4,   2};

    int Cp_[8], Kp_[8], Mpad_[8];
    short* Abf[8];
    for (int i = 0; i < 8; i++) {
        int K2 = kK[i] * kK[i];
        int Cp = (kC[i] < 8) ? 8 : kC[i];
        int gran = 32 * kSK[i];
        int Kp = (K2 * Cp + gran - 1) / gran * gran;   // SK-slice aligned
        int Mpad = (kM[i] + 63) & ~63;
        Cp_[i] = Cp; Kp_[i] = Kp; Mpad_[i] = Mpad;
        Abf[i] = (short*)allocb((size_t)Mpad * Kp * sizeof(short));
    }
    (void)ws_size; (void)in_sizes; (void)n_in; (void)out_size;

    struct LCfg { const float *s1, *s2; int C1, up; float delta; int widx; float* Y; };
    const float* input = (const float*)d_in[0];
    LCfg L[8] = {
        { input, nullptr,   6, 0, PI_F / 32.f,  1, x1  },
        { x1,    nullptr,  32, 0, PI_F / 16.f,  5, x2  },
        { x2,    nullptr,  64, 0, PI_F / 4.f,   9, x3  },
        { x3,    nullptr, 128, 0, PI_F / 4.f,  13, x31 },
        { x31,   nullptr, 128, 0, PI_F / 2.f,  17, x4  },
        { x4,    nullptr, 256, 0, PI_F / 2.f,  21, x41 },
        { x41,   x31,     256, 1, PI_F / 4.f,  25, x5  },
        { x5,    x2,      256, 1, PI_F / 8.f,  29, (float*)d_out },
    };

    // hoisted fused zero of non-aliased SK outputs
    {
        int n_x2 = B * 64 * 64 * 128;
        int n_x31 = B * 128 * 32 * 64;
        int n_out = B * 128 * 64 * 128;
        int tot = n_x2 + n_x31 + n_out;
        zero3_kernel<<<dim3((tot + 255) / 256), dim3(256), 0, stream>>>(
            x2, n_x2, x31, n_x31, (float*)d_out, n_out);
    }

    for (int i = 0; i < 8; i++) {
        const LCfg& c = L[i];
        int H = kH[i], W = kW[i], k = kK[i], st = kSt[i];
        int Ho = H / st, Wo = W / st;
        int K2 = k * k;
        int C  = kC[i], M = kM[i];
        int HW = Ho * Wo;
        int N  = B * HW;
        int lWo = __builtin_ctz(Wo), lHo = __builtin_ctz(Ho);
        const float* Wt   = (const float*)d_in[c.widx];
        const float* gam  = (const float*)d_in[c.widx + 2];
        const float* bet  = (const float*)d_in[c.widx + 3];
        int total = B * M * HW;

        int tn = Mpad_[i] * Kp_[i];
        wtrans_kernel<<<dim3((tn + 255) / 256), dim3(256), 0, stream>>>(
            Wt, Abf[i], M, Mpad_[i], K2, C, Cp_[i], Kp_[i], C * K2);

        int MWi = kMW[i], SKi = kSK[i];
        int nBlkM = Mpad_[i] / (64 * MWi);
        int nBlkN = N / BNT;
        int totalBlk = nBlkN * nBlkM * SKi;        // % 8 == 0 for all layers
        int lgM = __builtin_ctz(nBlkM);

        // inline zero only for Q-aliased outputs (x3, x4, x41, x5)
        if (SKi > 1 && i >= 2 && i <= 6 && c.Y != x31)
            zero_kernel<<<dim3((total + 255) / 256), dim3(256), 0, stream>>>(
                c.Y, total);

        #define CONV_ARGS Abf[i], c.s1, c.s2, part, nBlkN, \
            c.C1, C, Cp_[i], H, W, c.up, K2, k, st, lWo, lHo, c.delta, \
            c.Y, M, Kp_[i], N, lgM
        if      (MWi == 1 && SKi == 1)
            sconv_mfma_kernel<1,1><<<dim3(totalBlk), dim3(256), 0, stream>>>(CONV_ARGS);
        else if (MWi == 1 && SKi == 2)
            sconv_mfma_kernel<1,2><<<dim3(totalBlk), dim3(256), 0, stream>>>(CONV_ARGS);
        else if (MWi == 1 && SKi == 4)
            sconv_mfma_kernel<1,4><<<dim3(totalBlk), dim3(256), 0, stream>>>(CONV_ARGS);
        else if (MWi == 2 && SKi == 2)
            sconv_mfma_kernel<2,2><<<dim3(totalBlk), dim3(256), 0, stream>>>(CONV_ARGS);
        else
            sconv_mfma_kernel<2,4><<<dim3(totalBlk), dim3(256), 0, stream>>>(CONV_ARGS);
        #undef CONV_ARGS

        if (SKi > 1) {
            bn_stats8_kernel<<<dim3(M, 8), dim3(256), 0, stream>>>(
                c.Y, part, M, HW, B);
            bn_apply_sk_kernel<<<dim3(total / 256), dim3(256), 0, stream>>>(
                c.Y, part, gam, bet, M, HW, N, total);
        } else {
            bn_finalize_kernel<<<dim3(M), dim3(256), 0, stream>>>(
                part, scSf, gam, bet, nBlkN, N);
            bn_apply_kernel<<<dim3(total / 256), dim3(256), 0, stream>>>(
                c.Y, scSf, M, HW, total);
        }
    }
}